// Round 12
// baseline (892.688 us; speedup 1.0000x reference)
//
#include <hip/hip_runtime.h>

// ============================================================================
// ImprovedMoE R12 = R11 + software-pipelined A prefetch inside each ck:
//   rolling register buffer of PF taps (PF=3 for MT=1, PF=2 for MT=2);
//   tap t issues tap t+PF's global loads before its MFMAs -> A-load latency
//   hidden under MFMA work (R11 showed VGPR=52, compiler wasn't hoisting).
//   conv3/4 OCC 4->3 to make register room for the pipeline (no spill).
// B staged in LDS per ck (R10); blocked layouts; zero-pad sentinel halo.
// ============================================================================

typedef _Float16 h16;
typedef _Float16 half8 __attribute__((ext_vector_type(8)));
typedef float f32x16 __attribute__((ext_vector_type(16)));

__device__ __forceinline__ void split2f(float x, h16& hh, h16& ll) {
  h16 a = (h16)x;
  hh = a;
  ll = (h16)(x - (float)a);
}

// ---- fused prep: zero pads + conv1 wt transpose + conv2..6 weight split ----
// wsplit layout: wh/wl[ck][tap][cob][half][co64][c8]
__global__ void prep_all_k(const float* __restrict__ cw1, const float* __restrict__ cw2,
                           const float* __restrict__ cw3, const float* __restrict__ cw4,
                           const float* __restrict__ cw5, const float* __restrict__ cw6,
                           float* __restrict__ wt1t, h16* __restrict__ wh, h16* __restrict__ wl,
                           h16* p0, h16* p1, h16* p2, h16* p3) {
  int idx = blockIdx.x * 256 + threadIdx.x;
  if (idx < 64) {
    h16* p = (idx < 16) ? p0 : (idx < 32) ? p1 : (idx < 48) ? p2 : p3;
    p[idx & 15] = (h16)0.f;
    return;
  }
  idx -= 64;
  if (idx < 1728) {
    int co = idx % 64, r = idx / 64;
    wt1t[idx] = cw1[(size_t)co * 27 + r];
    return;
  }
  idx -= 1728;
  const float* w; int CIN, COUT; size_t off;
  if (idx < 36864)        { w = cw2; CIN = 64;  COUT = 64;  off = 0; }
  else if (idx < 110592)  { w = cw3; CIN = 64;  COUT = 128; off = 36864;  idx -= 36864; }
  else if (idx < 258048)  { w = cw4; CIN = 128; COUT = 128; off = 110592; idx -= 110592; }
  else if (idx < 552960)  { w = cw5; CIN = 128; COUT = 256; off = 258048; idx -= 258048; }
  else if (idx < 1142784) { w = cw6; CIN = 256; COUT = 256; off = 552960; idx -= 552960; }
  else return;
  int KCOB = COUT >> 6;
  int lidx = idx;
  int c8   = idx & 7;
  int t    = idx >> 3;
  int co64 = t & 63;  t >>= 6;
  int half = t & 1;   t >>= 1;
  int cob  = t % KCOB; t /= KCOB;
  int tap  = t % 9;
  int ck   = t / 9;
  int ci = ck * 16 + half * 8 + c8;
  int co = cob * 64 + co64;
  float v = w[((size_t)co * CIN + ci) * 9 + tap];
  split2f(v, wh[off + lidx], wl[off + lidx]);
}

// ---- conv1: 3->64, 32x32, fp32 vector; outputs blocked hi/lo planes (+16) ----
__global__ __launch_bounds__(256) void conv1_k(
    const float* __restrict__ x, const float* __restrict__ wt,
    const float* __restrict__ cb, const float* __restrict__ bns,
    const float* __restrict__ bnb, h16* __restrict__ oh, h16* __restrict__ ol)
{
  __shared__ float sx[3 * 34 * 34];
  const int tid = threadIdx.x;
  const int img = blockIdx.x;
  for (int idx = tid; idx < 3 * 34 * 34; idx += 256) {
    int xx = idx % 34;
    int t  = idx / 34;
    int rr = t % 34;
    int c  = t / 34;
    int gr = rr - 1, gx = xx - 1;
    float v = 0.f;
    if (gr >= 0 && gr < 32 && gx >= 0 && gx < 32)
      v = x[((size_t)(img * 3 + c) * 32 + gr) * 32 + gx];
    sx[(c * 34 + rr) * 34 + xx] = v;
  }
  __syncthreads();
#pragma unroll 1
  for (int k = 0; k < 4; ++k) {
    int px = k * 256 + tid;
    int yy = px >> 5, xx = px & 31;
    float in27[27];
#pragma unroll
    for (int c = 0; c < 3; ++c)
#pragma unroll
      for (int dy = 0; dy < 3; ++dy)
#pragma unroll
        for (int dx = 0; dx < 3; ++dx)
          in27[c * 9 + dy * 3 + dx] = sx[(c * 34 + yy + dy) * 34 + xx + dx];
#pragma unroll 1
    for (int cbk = 0; cbk < 4; ++cbk) {
      h16 hb[16], lb[16];
#pragma unroll
      for (int j = 0; j < 16; ++j) {
        int co = cbk * 16 + j;
        float acc = 0.f;
#pragma unroll
        for (int t = 0; t < 27; ++t) acc = fmaf(in27[t], wt[t * 64 + co], acc);
        float s = bns[co];
        float yv = fmaxf(fmaf(acc + cb[co], s, bnb[co]), 0.f);
        split2f(yv, hb[j], lb[j]);
      }
      size_t o = 16 + ((size_t)(img * 4 + cbk) * 1024 + px) * 16;
      *(half8*)&oh[o]     = *(half8*)&hb[0];
      *(half8*)&oh[o + 8] = *(half8*)&hb[8];
      *(half8*)&ol[o]     = *(half8*)&lb[0];
      *(half8*)&ol[o + 8] = *(half8*)&lb[8];
    }
  }
}

// ---------------------------------------------------------------------------
// MFMA conv: 3x3 SAME, fp16x2-split, tap-decomposed implicit GEMM.
// B staged in LDS per ck; A direct-from-global with PF-deep register
// prefetch pipeline; halo lanes load the 16-elt zero pad at plane start.
// 4 waves/block on one 64-co block; each wave: MT m-tiles x 2 n-tiles.
// ---------------------------------------------------------------------------
template<int H, int W, int CIN, int COUT, int MT, int POOL, int OCC>
__global__ __launch_bounds__(256, OCC) void conv_mfma(
    const h16* __restrict__ Ah, const h16* __restrict__ Al,
    const h16* __restrict__ Wh, const h16* __restrict__ Wl,
    const float* __restrict__ cb, const float* __restrict__ bns,
    const float* __restrict__ bnb,
    h16* __restrict__ Oh, h16* __restrict__ Ol, float* __restrict__ feats)
{
  constexpr int TPI  = (H * W) / 32;
  constexpr int RPT  = 32 / W;
  constexpr int IPB  = (4 * MT * 32 >= H * W) ? (4 * MT * 32) / (H * W) : 1;
  constexpr int KC   = CIN / 16;
  constexpr int HW   = H * W;
  constexpr int KCO  = COUT / 16;
  constexpr int KCOB = COUT / 64;
  constexpr int LOGW = (W == 32) ? 5 : (W == 16) ? 4 : 3;
  constexpr int PF   = (MT == 1) ? 3 : 2;   // A-prefetch depth (taps in flight)

  __shared__ h16 sBh[9 * 2 * 64 * 8];   // [tap][half][co64][c8], 18.4 KB
  __shared__ h16 sBl[9 * 2 * 64 * 8];
  __shared__ float sRed[(POOL == 2 && MT == 1) ? 256 : 1];

  const int tid  = threadIdx.x;
  const int lane = tid & 63;
  const int wave = tid >> 6;
  const int half = lane >> 5;
  const int col  = lane & 31;
  const int cob  = blockIdx.z;
  const int co0  = cob * 64;

  int aoff[MT], ty[MT], tx[MT], img_t[MT], rw0[MT];
#pragma unroll
  for (int t = 0; t < MT; ++t) {
    int gt   = blockIdx.y * (4 * MT) + wave * MT + t;
    int img  = blockIdx.x * IPB + gt / TPI;
    int row0 = (gt % TPI) * RPT;
    int y = row0 + (col >> LOGW);
    int x = col & (W - 1);
    img_t[t] = img; rw0[t] = row0; ty[t] = y; tx[t] = x;
    aoff[t] = 16 + ((img * KC) * HW + y * W + x) * 16 + half * 8;
  }

  f32x16 acc[MT][2];
#pragma unroll
  for (int t = 0; t < MT; ++t)
#pragma unroll
    for (int n = 0; n < 2; ++n)
#pragma unroll
      for (int i = 0; i < 16; ++i) acc[t][n][i] = 0.f;

#pragma unroll 1
  for (int ck = 0; ck < KC; ++ck) {
    // ---- stage B slice for this (ck, cob): 9 taps x hi/lo, linear copy ----
    __syncthreads();
#pragma unroll
    for (int i = 0; i < 5; ++i) {
      int id = tid + i * 256;                  // 1152 x 16B chunks per plane
      if (id < 1152) {
        int src = ((ck * 9 + (id >> 7)) * KCOB + cob) * 1024 + (id & 127) * 8;
        *(half8*)&sBh[id * 8] = *(const half8*)(Wh + src);
        *(half8*)&sBl[id * 8] = *(const half8*)(Wl + src);
      }
    }
    __syncthreads();

    const int ckoA = ck * (HW * 16);

    // ---- A prefetch pipeline: prologue loads taps 0..PF-1 ----
    half8 pah[PF][MT], pal[PF][MT];
#pragma unroll
    for (int pt = 0; pt < PF; ++pt) {
      const int dy = pt / 3 - 1, dx = pt % 3 - 1;
      const int ashift = (dy * W + dx) * 16;
#pragma unroll
      for (int t = 0; t < MT; ++t) {
        bool v = ((unsigned)(ty[t] + dy) < (unsigned)H) &&
                 ((unsigned)(tx[t] + dx) < (unsigned)W);
        int ai = v ? (aoff[t] + ckoA + ashift) : (half * 8);
        pah[pt][t] = *(const half8*)(Ah + ai);
        pal[pt][t] = *(const half8*)(Al + ai);
      }
    }

#pragma unroll
    for (int tap = 0; tap < 9; ++tap) {
      const int buf = tap % PF;
      half8 bh[2], bl[2];
#pragma unroll
      for (int n = 0; n < 2; ++n) {
        int bi = ((tap * 2 + half) * 64 + n * 32 + col) * 8;
        bh[n] = *(const half8*)&sBh[bi];
        bl[n] = *(const half8*)&sBl[bi];
      }
      // consume current tap's operands into temps, then refill the slot
      half8 cah[MT], cal[MT];
#pragma unroll
      for (int t = 0; t < MT; ++t) { cah[t] = pah[buf][t]; cal[t] = pal[buf][t]; }
      if (tap + PF < 9) {
        const int pt = tap + PF;
        const int dy = pt / 3 - 1, dx = pt % 3 - 1;
        const int ashift = (dy * W + dx) * 16;
#pragma unroll
        for (int t = 0; t < MT; ++t) {
          bool v = ((unsigned)(ty[t] + dy) < (unsigned)H) &&
                   ((unsigned)(tx[t] + dx) < (unsigned)W);
          int ai = v ? (aoff[t] + ckoA + ashift) : (half * 8);
          pah[buf][t] = *(const half8*)(Ah + ai);
          pal[buf][t] = *(const half8*)(Al + ai);
        }
      }
#pragma unroll
      for (int t = 0; t < MT; ++t)
#pragma unroll
        for (int n = 0; n < 2; ++n) {
          acc[t][n] = __builtin_amdgcn_mfma_f32_32x32x16_f16(cah[t], bh[n], acc[t][n], 0, 0, 0);
          acc[t][n] = __builtin_amdgcn_mfma_f32_32x32x16_f16(cal[t], bh[n], acc[t][n], 0, 0, 0);
          acc[t][n] = __builtin_amdgcn_mfma_f32_32x32x16_f16(cah[t], bl[n], acc[t][n], 0, 0, 0);
        }
    }
  }

  // ---- epilogue: y = acc*s + (cb*s+bb), relu, pool, split-store (blocked+16) ----
#pragma unroll
  for (int n = 0; n < 2; ++n) {
    const int co = co0 + n * 32 + col;
    const float es = bns[co];
    const float eb = fmaf(cb[co], es, bnb[co]);
    const int cko = co >> 4, c16 = co & 15;

    if constexpr (POOL == 0) {
#pragma unroll
      for (int t = 0; t < MT; ++t) {
#pragma unroll
        for (int r = 0; r < 16; ++r) {
          float v = fmaxf(fmaf(acc[t][n][r], es, eb), 0.f);
          int m = (r & 3) + 4 * half + 8 * (r >> 2);
          int y = rw0[t] + (m >> LOGW);
          int x = m & (W - 1);
          size_t oi = 16 + ((size_t)(img_t[t] * KCO + cko) * HW + y * W + x) * 16 + c16;
          h16 hh, ll; split2f(v, hh, ll);
          Oh[oi] = hh; Ol[oi] = ll;
        }
      }
    } else if constexpr (POOL == 1 && RPT == 1) {   // conv2: y-pair across tiles
      constexpr int HWq = (H / 2) * (W / 2);
#pragma unroll
      for (int tp = 0; tp < MT / 2; ++tp) {
        const int t0 = 2 * tp, t1 = 2 * tp + 1;
        const int yq = rw0[t0] >> 1;
#pragma unroll
        for (int r = 0; r < 16; r += 2) {
          float v00 = fmaxf(fmaf(acc[t0][n][r],     es, eb), 0.f);
          float v01 = fmaxf(fmaf(acc[t0][n][r + 1], es, eb), 0.f);
          float v10 = fmaxf(fmaf(acc[t1][n][r],     es, eb), 0.f);
          float v11 = fmaxf(fmaf(acc[t1][n][r + 1], es, eb), 0.f);
          float mv = fmaxf(fmaxf(v00, v01), fmaxf(v10, v11));
          int xq = ((r & 3) >> 1) + 2 * half + 4 * (r >> 2);
          size_t oi = 16 + ((size_t)(img_t[t0] * KCO + cko) * HWq + yq * (W / 2) + xq) * 16 + c16;
          h16 hh, ll; split2f(mv, hh, ll);
          Oh[oi] = hh; Ol[oi] = ll;
        }
      }
    } else if constexpr (POOL == 1) {               // conv4 (RPT==2): intra-reg
      constexpr int HWq = (H / 2) * (W / 2);
#pragma unroll
      for (int t = 0; t < MT; ++t) {
        const int yq = rw0[t] >> 1;
#pragma unroll
        for (int r = 0; r < 8; r += 2) {
          float v00 = fmaxf(fmaf(acc[t][n][r],     es, eb), 0.f);
          float v01 = fmaxf(fmaf(acc[t][n][r + 1], es, eb), 0.f);
          float v10 = fmaxf(fmaf(acc[t][n][r + 8], es, eb), 0.f);
          float v11 = fmaxf(fmaf(acc[t][n][r + 9], es, eb), 0.f);
          float mv = fmaxf(fmaxf(v00, v01), fmaxf(v10, v11));
          int xq = ((r & 3) >> 1) + 2 * half + 4 * (r >> 2);
          size_t oi = 16 + ((size_t)(img_t[t] * KCO + cko) * HWq + yq * (W / 2) + xq) * 16 + c16;
          h16 hh, ll; split2f(mv, hh, ll);
          Oh[oi] = hh; Ol[oi] = ll;
        }
      }
    } else if constexpr (POOL == 2 && MT == 1) {    // conv6: 2 waves share an image
      float s = 0.f;
#pragma unroll
      for (int r = 0; r < 16; ++r)
        s += fmaxf(fmaf(acc[0][n][r], es, eb), 0.f);
      s += __shfl_xor(s, 32, 64);                   // full 32-px tile sum
      if (half == 0) sRed[wave * 64 + n * 32 + col] = s;
    } else if constexpr (POOL == 2) {               // MT==2: full image per wave
      float s = 0.f;
#pragma unroll
      for (int t = 0; t < MT; ++t)
#pragma unroll
        for (int r = 0; r < 16; ++r)
          s += fmaxf(fmaf(acc[t][n][r], es, eb), 0.f);
      s += __shfl_xor(s, 32, 64);
      if (half == 0) feats[(size_t)img_t[0] * 256 + co] = s * (1.f / 64.f);
    }
  }

  if constexpr (POOL == 2 && MT == 1) {
    __syncthreads();
    if (tid < 128) {
      int li = tid >> 6, co_l = tid & 63;
      float s = sRed[(li * 2) * 64 + co_l] + sRed[(li * 2 + 1) * 64 + co_l];
      feats[(size_t)(blockIdx.x * 2 + li) * 256 + co0 + co_l] = s * (1.f / 64.f);
    }
  }
}

// ---------------------------------------------------------------------------
// Batched head GEMM (R1, verified).
// ---------------------------------------------------------------------------
template<int O, int K, int LN, int RELU>
__global__ __launch_bounds__(256, 4) void gemm_head(
    const float* __restrict__ A, size_t aStrideE,
    const float* __restrict__ Wm, const float* __restrict__ bias,
    const float* __restrict__ g, const float* __restrict__ bb,
    float* __restrict__ out)
{
  constexpr int KC  = (O >= 256) ? 32 : 64;
  constexpr int WST = O + 4;
  constexpr int TO  = O / 16;
  __shared__ float sA[KC * 68];
  __shared__ float sW[KC * WST];
  __shared__ float mArr[64], rArr[64];

  const int tid  = threadIdx.x;
  const int lane = tid & 63;
  const int wave = tid >> 6;
  const int e    = blockIdx.y;
  const int b0g  = blockIdx.x * 64;
  const int bl   = (lane & 15) * 4;
  const int ol   = wave * (O / 4) + (lane >> 4) * TO;

  const float* Ae = A + (size_t)e * aStrideE;
  const float* We = Wm + (size_t)e * O * K;

  float acc[4][TO];
#pragma unroll
  for (int i = 0; i < 4; ++i)
#pragma unroll
    for (int j = 0; j < TO; ++j) acc[i][j] = 0.f;

  for (int k0 = 0; k0 < K; k0 += KC) {
    for (int idx = tid; idx < 64 * KC; idx += 256) {
      int kk = idx % KC, bb_ = idx / KC;
      sA[kk * 68 + bb_] = Ae[(size_t)(b0g + bb_) * K + k0 + kk];
    }
    for (int idx = tid; idx < O * KC; idx += 256) {
      int kk = idx % KC, oo = idx / KC;
      sW[kk * WST + oo] = We[(size_t)oo * K + k0 + kk];
    }
    __syncthreads();
#pragma unroll 4
    for (int kk = 0; kk < KC; ++kk) {
      float4 av = *(const float4*)&sA[kk * 68 + bl];
      float a4[4] = {av.x, av.y, av.z, av.w};
#pragma unroll
      for (int j4 = 0; j4 < TO; j4 += 4) {
        float4 wv = *(const float4*)&sW[kk * WST + ol + j4];
        float w4[4] = {wv.x, wv.y, wv.z, wv.w};
#pragma unroll
        for (int i = 0; i < 4; ++i)
#pragma unroll
          for (int jj = 0; jj < 4; ++jj)
            acc[i][j4 + jj] = fmaf(a4[i], w4[jj], acc[i][j4 + jj]);
      }
    }
    __syncthreads();
  }

  const float* bi = bias + (size_t)e * O;
#pragma unroll
  for (int i = 0; i < 4; ++i)
#pragma unroll
    for (int j = 0; j < TO; ++j) acc[i][j] += bi[ol + j];

  if constexpr (LN) {
    float* redS = sA;
    float* redQ = sA + 1024;
    const int grp = wave * 4 + (lane >> 4);
#pragma unroll
    for (int i = 0; i < 4; ++i) {
      float s = 0.f, q = 0.f;
#pragma unroll
      for (int j = 0; j < TO; ++j) { s += acc[i][j]; q += acc[i][j] * acc[i][j]; }
      redS[(bl + i) * 16 + grp] = s;
      redQ[(bl + i) * 16 + grp] = q;
    }
    __syncthreads();
    if (tid < 64) {
      float s = 0.f, q = 0.f;
#pragma unroll
      for (int gi = 0; gi < 16; ++gi) { s += redS[tid * 16 + gi]; q += redQ[tid * 16 + gi]; }
      float mean = s * (1.f / O);
      float var  = q * (1.f / O) - mean * mean;
      mArr[tid] = mean;
      rArr[tid] = rsqrtf(var + 1e-5f);
    }
    __syncthreads();
    const float* gp  = g + (size_t)e * O;
    const float* bbp = bb + (size_t)e * O;
#pragma unroll
    for (int i = 0; i < 4; ++i) {
      float mean = mArr[bl + i], rstd = rArr[bl + i];
#pragma unroll
      for (int j = 0; j < TO; ++j)
        acc[i][j] = (acc[i][j] - mean) * rstd * gp[ol + j] + bbp[ol + j];
    }
  }
  if constexpr (RELU) {
#pragma unroll
    for (int i = 0; i < 4; ++i)
#pragma unroll
      for (int j = 0; j < TO; ++j) acc[i][j] = fmaxf(acc[i][j], 0.f);
  }
#pragma unroll
  for (int i = 0; i < 4; ++i) {
    float* op = out + ((size_t)e * 512 + b0g + bl + i) * O + ol;
#pragma unroll
    for (int j4 = 0; j4 < TO; j4 += 4)
      *(float4*)(op + j4) = make_float4(acc[i][j4], acc[i][j4 + 1], acc[i][j4 + 2], acc[i][j4 + 3]);
  }
}

__global__ void cls_softmax_k(const float* __restrict__ embeds,
                              const float* __restrict__ cw,
                              const float* __restrict__ cbias,
                              float* __restrict__ logits_e,
                              float* __restrict__ conf)
{
  int wv   = (blockIdx.x * 256 + threadIdx.x) >> 6;
  int lane = threadIdx.x & 63;
  int b = wv >> 4, e = wv & 15;
  const float* ep = embeds + ((size_t)e * 512 + b) * 128;
  float e0 = ep[lane], e1 = ep[lane + 64];
  float l[10];
#pragma unroll
  for (int o = 0; o < 10; ++o) {
    const float* wp = cw + ((size_t)e * 10 + o) * 128;
    l[o] = e0 * wp[lane] + e1 * wp[lane + 64];
  }
#pragma unroll
  for (int s = 32; s >= 1; s >>= 1)
#pragma unroll
    for (int o = 0; o < 10; ++o) l[o] += __shfl_xor(l[o], s, 64);
#pragma unroll
  for (int o = 0; o < 10; ++o) l[o] += cbias[e * 10 + o];
  float m = l[0];
#pragma unroll
  for (int o = 1; o < 10; ++o) m = fmaxf(m, l[o]);
  float p[10], sum = 0.f;
#pragma unroll
  for (int o = 0; o < 10; ++o) { p[o] = expf(l[o] - m); sum += p[o]; }
  float inv = 1.f / sum, ent = 0.f;
#pragma unroll
  for (int o = 0; o < 10; ++o) { float pp = p[o] * inv; ent -= pp * logf(pp + 1e-12f); }
  if (lane == 0) {
    conf[b * 16 + e] = -ent;
#pragma unroll
    for (int o = 0; o < 10; ++o) logits_e[((size_t)b * 16 + e) * 10 + o] = l[o];
  }
}

__global__ void gate23_k(const float* __restrict__ g1, const float* __restrict__ w2,
                         const float* __restrict__ b2, const float* __restrict__ w3,
                         const float* __restrict__ b3, float* __restrict__ scores)
{
  int wv   = (blockIdx.x * 256 + threadIdx.x) >> 6;
  int lane = threadIdx.x & 63;
  int b = wv >> 4, e = wv & 15;
  float gv = g1[((size_t)e * 512 + b) * 64 + lane];
  const float* w3p = w3 + e * 32;
  float sc = 0.f;
#pragma unroll
  for (int o = 0; o < 32; ++o) {
    float t = gv * w2[((size_t)e * 32 + o) * 64 + lane];
#pragma unroll
    for (int s = 32; s >= 1; s >>= 1) t += __shfl_xor(t, s, 64);
    float g2v = fmaxf(t + b2[e * 32 + o], 0.f);
    sc = fmaf(g2v, w3p[o], sc);
  }
  if (lane == 0) scores[b * 16 + e] = sc + b3[e];
}

__global__ void routing_k(const float* __restrict__ scores, const float* __restrict__ conf,
                          const float* __restrict__ logits_e, float* __restrict__ out)
{
  __shared__ int t2[512];
  __shared__ int chs[512];
  const int tid = threadIdx.x;

  if (tid < 512) {
    int b = tid;
    float v0 = -3.4e38f, v1 = -3.4e38f;
    int i0 = 0, i1 = 0;
#pragma unroll
    for (int e = 0; e < 16; ++e) {
      float s = scores[b * 16 + e];
      float c = conf[b * 16 + e];
      float v = 0.7f * s + 0.3f * c - 0.125f;
      out[5120 + b * 16 + e] = v;
      if (v > v0) { v1 = v0; i1 = i0; v0 = v; i0 = e; }
      else if (v > v1) { v1 = v; i1 = e; }
    }
    t2[b] = i0 | (i1 << 8);
  }
  __syncthreads();

  if (tid < 64) {
    int lane = tid;
    int cnt = 0;
    int pk[8];
#pragma unroll
    for (int k = 0; k < 8; ++k) pk[k] = t2[k * 64 + lane];
#pragma unroll 1
    for (int k = 0; k < 8; ++k) {
      for (int j = 0; j < 64; ++j) {
        int pair = __shfl(pk[k], j, 64);
        int i0 = pair & 0xff, i1 = (pair >> 8) & 0xff;
        int c0 = __shfl(cnt, i0, 64);
        int c1 = __shfl(cnt, i1, 64);
        int ch = (c0 < 64) ? i0 : ((c1 < 64) ? i1 : ((c0 <= c1) ? i0 : i1));
        cnt += (lane == ch) ? 1 : 0;
        if (lane == 0) chs[k * 64 + j] = ch;
      }
    }
  }
  __syncthreads();

  if (tid < 512) {
    int b = tid;
    int ch = chs[b];
#pragma unroll
    for (int e = 0; e < 16; ++e)
      out[13312 + b * 16 + e] = (e == ch) ? 1.0f : 0.0f;
#pragma unroll
    for (int o = 0; o < 10; ++o)
      out[b * 10 + o] = logits_e[((size_t)b * 16 + ch) * 10 + o];
  }
}

// ============================================================================
extern "C" void kernel_launch(void* const* d_in, const int* in_sizes, int n_in,
                              void* d_out, int out_size, void* d_ws, size_t ws_size,
                              hipStream_t stream) {
  (void)in_sizes; (void)n_in; (void)out_size; (void)ws_size;

  const float* x = (const float*)d_in[0];
  const float *cw[6], *cbv[6], *bsv[6], *bbv[6];
  for (int i = 0; i < 6; ++i) {
    cw[i]  = (const float*)d_in[1 + 4 * i];
    cbv[i] = (const float*)d_in[2 + 4 * i];
    bsv[i] = (const float*)d_in[3 + 4 * i];
    bbv[i] = (const float*)d_in[4 + 4 * i];
  }
  const float* gate_w1  = (const float*)d_in[25];
  const float* gate_b1  = (const float*)d_in[26];
  const float* gate_g1  = (const float*)d_in[27];
  const float* gate_bb1 = (const float*)d_in[28];
  const float* gate_w2  = (const float*)d_in[29];
  const float* gate_b2  = (const float*)d_in[30];
  const float* gate_w3  = (const float*)d_in[31];
  const float* gate_b3  = (const float*)d_in[32];
  const float* exp_w1   = (const float*)d_in[33];
  const float* exp_b1   = (const float*)d_in[34];
  const float* exp_g1   = (const float*)d_in[35];
  const float* exp_bb1  = (const float*)d_in[36];
  const float* exp_w2   = (const float*)d_in[37];
  const float* exp_b2   = (const float*)d_in[38];
  const float* exp_g2   = (const float*)d_in[39];
  const float* exp_bb2  = (const float*)d_in[40];
  const float* exp_w3   = (const float*)d_in[41];
  const float* exp_b3   = (const float*)d_in[42];
  const float* cls_w    = (const float*)d_in[43];
  const float* cls_b    = (const float*)d_in[44];

  char* wsb = (char*)d_ws;
  const size_t off_wt1t = 0;
  const size_t off_whi  = 6912;
  const size_t off_wlo  = 2292480;
  const size_t off_Phi  = 4578048;
  const size_t off_Plo  = 71687168;
  const size_t off_Qhi  = 138796288;
  const size_t off_Qlo  = 155573760;
  const size_t off_feats= 172351232;
  const size_t off_h1   = 138796288 + 512;
  const size_t off_h2   = off_h1 + 8388608;
  const size_t off_emb  = off_h2 + 4194304;
  const size_t off_g1   = off_emb + 4194304;
  const size_t off_lg   = off_g1 + 2097152;
  const size_t off_conf = off_lg + 327680;
  const size_t off_sc   = off_conf + 32768;

  float* wt1t = (float*)(wsb + off_wt1t);
  h16* whi = (h16*)(wsb + off_whi);
  h16* wlo = (h16*)(wsb + off_wlo);
  h16* Phi = (h16*)(wsb + off_Phi);
  h16* Plo = (h16*)(wsb + off_Plo);
  h16* Qhi = (h16*)(wsb + off_Qhi);
  h16* Qlo = (h16*)(wsb + off_Qlo);
  float* feats = (float*)(wsb + off_feats);
  float* h1 = (float*)(wsb + off_h1);
  float* h2 = (float*)(wsb + off_h2);
  float* emb = (float*)(wsb + off_emb);
  float* g1 = (float*)(wsb + off_g1);
  float* lg = (float*)(wsb + off_lg);
  float* conf = (float*)(wsb + off_conf);
  float* sc = (float*)(wsb + off_sc);

  const size_t wo2 = 0;
  const size_t wo3 = 36864;
  const size_t wo4 = 110592;
  const size_t wo5 = 258048;
  const size_t wo6 = 552960;

  // ---- fused prep (pads + wt1 transpose + all weight splits) ----
  prep_all_k<<<4471, 256, 0, stream>>>(cw[0], cw[1], cw[2], cw[3], cw[4], cw[5],
                                       wt1t, whi, wlo, Phi, Plo, Qhi, Qlo);

  // ---- trunk ----
  conv1_k<<<512, 256, 0, stream>>>(x, wt1t, cbv[0], bsv[0], bbv[0], Phi, Plo);
  // <H, W, CIN, COUT, MT, POOL, OCC>
  conv_mfma<32, 32, 64, 64, 2, 1, 3><<<dim3(512, 4, 1), 256, 0, stream>>>(
      Phi, Plo, whi + wo2, wlo + wo2, cbv[1], bsv[1], bbv[1], Qhi, Qlo, nullptr);
  conv_mfma<16, 16, 64, 128, 2, 0, 3><<<dim3(512, 1, 2), 256, 0, stream>>>(
      Qhi, Qlo, whi + wo3, wlo + wo3, cbv[2], bsv[2], bbv[2], Phi, Plo, nullptr);
  conv_mfma<16, 16, 128, 128, 2, 1, 3><<<dim3(512, 1, 2), 256, 0, stream>>>(
      Phi, Plo, whi + wo4, wlo + wo4, cbv[3], bsv[3], bbv[3], Qhi, Qlo, nullptr);
  conv_mfma<8, 8, 128, 256, 1, 0, 4><<<dim3(256, 1, 4), 256, 0, stream>>>(
      Qhi, Qlo, whi + wo5, wlo + wo5, cbv[4], bsv[4], bbv[4], Phi, Plo, nullptr);
  conv_mfma<8, 8, 256, 256, 1, 2, 4><<<dim3(256, 1, 4), 256, 0, stream>>>(
      Phi, Plo, whi + wo6, wlo + wo6, cbv[5], bsv[5], bbv[5], nullptr, nullptr, feats);

  // ---- experts ----
  gemm_head<256, 256, 1, 1><<<dim3(8, 16), 256, 0, stream>>>(
      feats, (size_t)0, exp_w1, exp_b1, exp_g1, exp_bb1, h1);
  gemm_head<128, 256, 1, 1><<<dim3(8, 16), 256, 0, stream>>>(
      h1, (size_t)512 * 256, exp_w2, exp_b2, exp_g2, exp_bb2, h2);
  gemm_head<128, 128, 0, 0><<<dim3(8, 16), 256, 0, stream>>>(
      h2, (size_t)512 * 128, exp_w3, exp_b3, nullptr, nullptr, emb);
  cls_softmax_k<<<2048, 256, 0, stream>>>(emb, cls_w, cls_b, lg, conf);

  // ---- gates ----
  gemm_head<64, 256, 1, 1><<<dim3(8, 16), 256, 0, stream>>>(
      feats, (size_t)0, gate_w1, gate_b1, gate_g1, gate_bb1, g1);
  gate23_k<<<2048, 256, 0, stream>>>(g1, gate_w2, gate_b2, gate_w3, gate_b3, sc);

  // ---- routing + outputs ----
  routing_k<<<1, 512, 0, stream>>>(sc, conf, lg, (float*)d_out);
}

// Round 13
// 815.551 us; speedup vs baseline: 1.0946x; 1.0946x over previous
//
#include <hip/hip_runtime.h>

// ============================================================================
// ImprovedMoE R13 = R12 with the Ah*Bl MFMA dropped:
//   D = (Ah+Al)*Bh  == exact activations x fp16-rounded weights.
//   Per-layer rel err ~2^-12 RMS, ~1e-3 end-to-end (measured-safe: 7.8e-3
//   passed in R4-R6 with routing intact; threshold 3.2e-2).
//   Wins: 2 MFMAs/tap instead of 3 AND half the LDS B traffic (no sBl) --
//   R12 post-mortem showed the per-CU DS pipe (4 waves x full B slice per ck)
//   is what pins MfmaUtil at ~43%.
// B(hi) staged in LDS per ck; A hi/lo direct-from-global with PF prefetch.
// ============================================================================

typedef _Float16 h16;
typedef _Float16 half8 __attribute__((ext_vector_type(8)));
typedef float f32x16 __attribute__((ext_vector_type(16)));

__device__ __forceinline__ void split2f(float x, h16& hh, h16& ll) {
  h16 a = (h16)x;
  hh = a;
  ll = (h16)(x - (float)a);
}

// ---- fused prep: zero pads + conv1 wt transpose + conv2..6 weight split ----
// wsplit layout: wh[ck][tap][cob][half][co64][c8]  (wl kept for layout parity,
// unused by conv_mfma)
__global__ void prep_all_k(const float* __restrict__ cw1, const float* __restrict__ cw2,
                           const float* __restrict__ cw3, const float* __restrict__ cw4,
                           const float* __restrict__ cw5, const float* __restrict__ cw6,
                           float* __restrict__ wt1t, h16* __restrict__ wh, h16* __restrict__ wl,
                           h16* p0, h16* p1, h16* p2, h16* p3) {
  int idx = blockIdx.x * 256 + threadIdx.x;
  if (idx < 64) {
    h16* p = (idx < 16) ? p0 : (idx < 32) ? p1 : (idx < 48) ? p2 : p3;
    p[idx & 15] = (h16)0.f;
    return;
  }
  idx -= 64;
  if (idx < 1728) {
    int co = idx % 64, r = idx / 64;
    wt1t[idx] = cw1[(size_t)co * 27 + r];
    return;
  }
  idx -= 1728;
  const float* w; int CIN, COUT; size_t off;
  if (idx < 36864)        { w = cw2; CIN = 64;  COUT = 64;  off = 0; }
  else if (idx < 110592)  { w = cw3; CIN = 64;  COUT = 128; off = 36864;  idx -= 36864; }
  else if (idx < 258048)  { w = cw4; CIN = 128; COUT = 128; off = 110592; idx -= 110592; }
  else if (idx < 552960)  { w = cw5; CIN = 128; COUT = 256; off = 258048; idx -= 258048; }
  else if (idx < 1142784) { w = cw6; CIN = 256; COUT = 256; off = 552960; idx -= 552960; }
  else return;
  int KCOB = COUT >> 6;
  int lidx = idx;
  int c8   = idx & 7;
  int t    = idx >> 3;
  int co64 = t & 63;  t >>= 6;
  int half = t & 1;   t >>= 1;
  int cob  = t % KCOB; t /= KCOB;
  int tap  = t % 9;
  int ck   = t / 9;
  int ci = ck * 16 + half * 8 + c8;
  int co = cob * 64 + co64;
  float v = w[((size_t)co * CIN + ci) * 9 + tap];
  h16 hh, ll;
  split2f(v, hh, ll);
  wh[off + lidx] = hh;
  wl[off + lidx] = ll;   // unused downstream; kept for simplicity
}

// ---- conv1: 3->64, 32x32, fp32 vector; outputs blocked hi/lo planes (+16) ----
__global__ __launch_bounds__(256) void conv1_k(
    const float* __restrict__ x, const float* __restrict__ wt,
    const float* __restrict__ cb, const float* __restrict__ bns,
    const float* __restrict__ bnb, h16* __restrict__ oh, h16* __restrict__ ol)
{
  __shared__ float sx[3 * 34 * 34];
  const int tid = threadIdx.x;
  const int img = blockIdx.x;
  for (int idx = tid; idx < 3 * 34 * 34; idx += 256) {
    int xx = idx % 34;
    int t  = idx / 34;
    int rr = t % 34;
    int c  = t / 34;
    int gr = rr - 1, gx = xx - 1;
    float v = 0.f;
    if (gr >= 0 && gr < 32 && gx >= 0 && gx < 32)
      v = x[((size_t)(img * 3 + c) * 32 + gr) * 32 + gx];
    sx[(c * 34 + rr) * 34 + xx] = v;
  }
  __syncthreads();
#pragma unroll 1
  for (int k = 0; k < 4; ++k) {
    int px = k * 256 + tid;
    int yy = px >> 5, xx = px & 31;
    float in27[27];
#pragma unroll
    for (int c = 0; c < 3; ++c)
#pragma unroll
      for (int dy = 0; dy < 3; ++dy)
#pragma unroll
        for (int dx = 0; dx < 3; ++dx)
          in27[c * 9 + dy * 3 + dx] = sx[(c * 34 + yy + dy) * 34 + xx + dx];
#pragma unroll 1
    for (int cbk = 0; cbk < 4; ++cbk) {
      h16 hb[16], lb[16];
#pragma unroll
      for (int j = 0; j < 16; ++j) {
        int co = cbk * 16 + j;
        float acc = 0.f;
#pragma unroll
        for (int t = 0; t < 27; ++t) acc = fmaf(in27[t], wt[t * 64 + co], acc);
        float s = bns[co];
        float yv = fmaxf(fmaf(acc + cb[co], s, bnb[co]), 0.f);
        split2f(yv, hb[j], lb[j]);
      }
      size_t o = 16 + ((size_t)(img * 4 + cbk) * 1024 + px) * 16;
      *(half8*)&oh[o]     = *(half8*)&hb[0];
      *(half8*)&oh[o + 8] = *(half8*)&hb[8];
      *(half8*)&ol[o]     = *(half8*)&lb[0];
      *(half8*)&ol[o + 8] = *(half8*)&lb[8];
    }
  }
}

// ---------------------------------------------------------------------------
// MFMA conv: 3x3 SAME, tap-decomposed implicit GEMM.
// D = (Ah+Al)*Bh : 2 MFMAs per (tile,tap). B(hi) staged in LDS per ck;
// A hi/lo direct-from-global with PF-deep register prefetch; halo lanes
// load the 16-elt zero pad at plane start.
// 4 waves/block on one 64-co block; each wave: MT m-tiles x 2 n-tiles.
// ---------------------------------------------------------------------------
template<int H, int W, int CIN, int COUT, int MT, int POOL, int OCC>
__global__ __launch_bounds__(256, OCC) void conv_mfma(
    const h16* __restrict__ Ah, const h16* __restrict__ Al,
    const h16* __restrict__ Wh,
    const float* __restrict__ cb, const float* __restrict__ bns,
    const float* __restrict__ bnb,
    h16* __restrict__ Oh, h16* __restrict__ Ol, float* __restrict__ feats)
{
  constexpr int TPI  = (H * W) / 32;
  constexpr int RPT  = 32 / W;
  constexpr int IPB  = (4 * MT * 32 >= H * W) ? (4 * MT * 32) / (H * W) : 1;
  constexpr int KC   = CIN / 16;
  constexpr int HW   = H * W;
  constexpr int KCO  = COUT / 16;
  constexpr int KCOB = COUT / 64;
  constexpr int LOGW = (W == 32) ? 5 : (W == 16) ? 4 : 3;
  constexpr int PF   = (MT == 1) ? 3 : 2;   // A-prefetch depth (taps in flight)

  __shared__ h16 sBh[9 * 2 * 64 * 8];   // [tap][half][co64][c8], 18.4 KB
  __shared__ float sRed[(POOL == 2 && MT == 1) ? 256 : 1];

  const int tid  = threadIdx.x;
  const int lane = tid & 63;
  const int wave = tid >> 6;
  const int half = lane >> 5;
  const int col  = lane & 31;
  const int cob  = blockIdx.z;
  const int co0  = cob * 64;

  int aoff[MT], ty[MT], tx[MT], img_t[MT], rw0[MT];
#pragma unroll
  for (int t = 0; t < MT; ++t) {
    int gt   = blockIdx.y * (4 * MT) + wave * MT + t;
    int img  = blockIdx.x * IPB + gt / TPI;
    int row0 = (gt % TPI) * RPT;
    int y = row0 + (col >> LOGW);
    int x = col & (W - 1);
    img_t[t] = img; rw0[t] = row0; ty[t] = y; tx[t] = x;
    aoff[t] = 16 + ((img * KC) * HW + y * W + x) * 16 + half * 8;
  }

  f32x16 acc[MT][2];
#pragma unroll
  for (int t = 0; t < MT; ++t)
#pragma unroll
    for (int n = 0; n < 2; ++n)
#pragma unroll
      for (int i = 0; i < 16; ++i) acc[t][n][i] = 0.f;

#pragma unroll 1
  for (int ck = 0; ck < KC; ++ck) {
    // ---- stage B(hi) slice for this (ck, cob): 9 taps, linear copy ----
    __syncthreads();
#pragma unroll
    for (int i = 0; i < 5; ++i) {
      int id = tid + i * 256;                  // 1152 x 16B chunks
      if (id < 1152) {
        int src = ((ck * 9 + (id >> 7)) * KCOB + cob) * 1024 + (id & 127) * 8;
        *(half8*)&sBh[id * 8] = *(const half8*)(Wh + src);
      }
    }
    __syncthreads();

    const int ckoA = ck * (HW * 16);

    // ---- A prefetch pipeline: prologue loads taps 0..PF-1 ----
    half8 pah[PF][MT], pal[PF][MT];
#pragma unroll
    for (int pt = 0; pt < PF; ++pt) {
      const int dy = pt / 3 - 1, dx = pt % 3 - 1;
      const int ashift = (dy * W + dx) * 16;
#pragma unroll
      for (int t = 0; t < MT; ++t) {
        bool v = ((unsigned)(ty[t] + dy) < (unsigned)H) &&
                 ((unsigned)(tx[t] + dx) < (unsigned)W);
        int ai = v ? (aoff[t] + ckoA + ashift) : (half * 8);
        pah[pt][t] = *(const half8*)(Ah + ai);
        pal[pt][t] = *(const half8*)(Al + ai);
      }
    }

#pragma unroll
    for (int tap = 0; tap < 9; ++tap) {
      const int buf = tap % PF;
      half8 bh[2];
#pragma unroll
      for (int n = 0; n < 2; ++n) {
        int bi = ((tap * 2 + half) * 64 + n * 32 + col) * 8;
        bh[n] = *(const half8*)&sBh[bi];
      }
      half8 cah[MT], cal[MT];
#pragma unroll
      for (int t = 0; t < MT; ++t) { cah[t] = pah[buf][t]; cal[t] = pal[buf][t]; }
      if (tap + PF < 9) {
        const int pt = tap + PF;
        const int dy = pt / 3 - 1, dx = pt % 3 - 1;
        const int ashift = (dy * W + dx) * 16;
#pragma unroll
        for (int t = 0; t < MT; ++t) {
          bool v = ((unsigned)(ty[t] + dy) < (unsigned)H) &&
                   ((unsigned)(tx[t] + dx) < (unsigned)W);
          int ai = v ? (aoff[t] + ckoA + ashift) : (half * 8);
          pah[buf][t] = *(const half8*)(Ah + ai);
          pal[buf][t] = *(const half8*)(Al + ai);
        }
      }
#pragma unroll
      for (int t = 0; t < MT; ++t)
#pragma unroll
        for (int n = 0; n < 2; ++n) {
          acc[t][n] = __builtin_amdgcn_mfma_f32_32x32x16_f16(cah[t], bh[n], acc[t][n], 0, 0, 0);
          acc[t][n] = __builtin_amdgcn_mfma_f32_32x32x16_f16(cal[t], bh[n], acc[t][n], 0, 0, 0);
        }
    }
  }

  // ---- epilogue: y = acc*s + (cb*s+bb), relu, pool, split-store (blocked+16) ----
#pragma unroll
  for (int n = 0; n < 2; ++n) {
    const int co = co0 + n * 32 + col;
    const float es = bns[co];
    const float eb = fmaf(cb[co], es, bnb[co]);
    const int cko = co >> 4, c16 = co & 15;

    if constexpr (POOL == 0) {
#pragma unroll
      for (int t = 0; t < MT; ++t) {
#pragma unroll
        for (int r = 0; r < 16; ++r) {
          float v = fmaxf(fmaf(acc[t][n][r], es, eb), 0.f);
          int m = (r & 3) + 4 * half + 8 * (r >> 2);
          int y = rw0[t] + (m >> LOGW);
          int x = m & (W - 1);
          size_t oi = 16 + ((size_t)(img_t[t] * KCO + cko) * HW + y * W + x) * 16 + c16;
          h16 hh, ll; split2f(v, hh, ll);
          Oh[oi] = hh; Ol[oi] = ll;
        }
      }
    } else if constexpr (POOL == 1 && RPT == 1) {   // conv2: y-pair across tiles
      constexpr int HWq = (H / 2) * (W / 2);
#pragma unroll
      for (int tp = 0; tp < MT / 2; ++tp) {
        const int t0 = 2 * tp, t1 = 2 * tp + 1;
        const int yq = rw0[t0] >> 1;
#pragma unroll
        for (int r = 0; r < 16; r += 2) {
          float v00 = fmaxf(fmaf(acc[t0][n][r],     es, eb), 0.f);
          float v01 = fmaxf(fmaf(acc[t0][n][r + 1], es, eb), 0.f);
          float v10 = fmaxf(fmaf(acc[t1][n][r],     es, eb), 0.f);
          float v11 = fmaxf(fmaf(acc[t1][n][r + 1], es, eb), 0.f);
          float mv = fmaxf(fmaxf(v00, v01), fmaxf(v10, v11));
          int xq = ((r & 3) >> 1) + 2 * half + 4 * (r >> 2);
          size_t oi = 16 + ((size_t)(img_t[t0] * KCO + cko) * HWq + yq * (W / 2) + xq) * 16 + c16;
          h16 hh, ll; split2f(mv, hh, ll);
          Oh[oi] = hh; Ol[oi] = ll;
        }
      }
    } else if constexpr (POOL == 1) {               // conv4 (RPT==2): intra-reg
      constexpr int HWq = (H / 2) * (W / 2);
#pragma unroll
      for (int t = 0; t < MT; ++t) {
        const int yq = rw0[t] >> 1;
#pragma unroll
        for (int r = 0; r < 8; r += 2) {
          float v00 = fmaxf(fmaf(acc[t][n][r],     es, eb), 0.f);
          float v01 = fmaxf(fmaf(acc[t][n][r + 1], es, eb), 0.f);
          float v10 = fmaxf(fmaf(acc[t][n][r + 8], es, eb), 0.f);
          float v11 = fmaxf(fmaf(acc[t][n][r + 9], es, eb), 0.f);
          float mv = fmaxf(fmaxf(v00, v01), fmaxf(v10, v11));
          int xq = ((r & 3) >> 1) + 2 * half + 4 * (r >> 2);
          size_t oi = 16 + ((size_t)(img_t[t] * KCO + cko) * HWq + yq * (W / 2) + xq) * 16 + c16;
          h16 hh, ll; split2f(mv, hh, ll);
          Oh[oi] = hh; Ol[oi] = ll;
        }
      }
    } else if constexpr (POOL == 2 && MT == 1) {    // conv6: 2 waves share an image
      float s = 0.f;
#pragma unroll
      for (int r = 0; r < 16; ++r)
        s += fmaxf(fmaf(acc[0][n][r], es, eb), 0.f);
      s += __shfl_xor(s, 32, 64);                   // full 32-px tile sum
      if (half == 0) sRed[wave * 64 + n * 32 + col] = s;
    } else if constexpr (POOL == 2) {               // MT==2: full image per wave
      float s = 0.f;
#pragma unroll
      for (int t = 0; t < MT; ++t)
#pragma unroll
        for (int r = 0; r < 16; ++r)
          s += fmaxf(fmaf(acc[t][n][r], es, eb), 0.f);
      s += __shfl_xor(s, 32, 64);
      if (half == 0) feats[(size_t)img_t[0] * 256 + co] = s * (1.f / 64.f);
    }
  }

  if constexpr (POOL == 2 && MT == 1) {
    __syncthreads();
    if (tid < 128) {
      int li = tid >> 6, co_l = tid & 63;
      float s = sRed[(li * 2) * 64 + co_l] + sRed[(li * 2 + 1) * 64 + co_l];
      feats[(size_t)(blockIdx.x * 2 + li) * 256 + co0 + co_l] = s * (1.f / 64.f);
    }
  }
}

// ---------------------------------------------------------------------------
// Batched head GEMM (R1, verified).
// ---------------------------------------------------------------------------
template<int O, int K, int LN, int RELU>
__global__ __launch_bounds__(256, 4) void gemm_head(
    const float* __restrict__ A, size_t aStrideE,
    const float* __restrict__ Wm, const float* __restrict__ bias,
    const float* __restrict__ g, const float* __restrict__ bb,
    float* __restrict__ out)
{
  constexpr int KC  = (O >= 256) ? 32 : 64;
  constexpr int WST = O + 4;
  constexpr int TO  = O / 16;
  __shared__ float sA[KC * 68];
  __shared__ float sW[KC * WST];
  __shared__ float mArr[64], rArr[64];

  const int tid  = threadIdx.x;
  const int lane = tid & 63;
  const int wave = tid >> 6;
  const int e    = blockIdx.y;
  const int b0g  = blockIdx.x * 64;
  const int bl   = (lane & 15) * 4;
  const int ol   = wave * (O / 4) + (lane >> 4) * TO;

  const float* Ae = A + (size_t)e * aStrideE;
  const float* We = Wm + (size_t)e * O * K;

  float acc[4][TO];
#pragma unroll
  for (int i = 0; i < 4; ++i)
#pragma unroll
    for (int j = 0; j < TO; ++j) acc[i][j] = 0.f;

  for (int k0 = 0; k0 < K; k0 += KC) {
    for (int idx = tid; idx < 64 * KC; idx += 256) {
      int kk = idx % KC, bb_ = idx / KC;
      sA[kk * 68 + bb_] = Ae[(size_t)(b0g + bb_) * K + k0 + kk];
    }
    for (int idx = tid; idx < O * KC; idx += 256) {
      int kk = idx % KC, oo = idx / KC;
      sW[kk * WST + oo] = We[(size_t)oo * K + k0 + kk];
    }
    __syncthreads();
#pragma unroll 4
    for (int kk = 0; kk < KC; ++kk) {
      float4 av = *(const float4*)&sA[kk * 68 + bl];
      float a4[4] = {av.x, av.y, av.z, av.w};
#pragma unroll
      for (int j4 = 0; j4 < TO; j4 += 4) {
        float4 wv = *(const float4*)&sW[kk * WST + ol + j4];
        float w4[4] = {wv.x, wv.y, wv.z, wv.w};
#pragma unroll
        for (int i = 0; i < 4; ++i)
#pragma unroll
          for (int jj = 0; jj < 4; ++jj)
            acc[i][j4 + jj] = fmaf(a4[i], w4[jj], acc[i][j4 + jj]);
      }
    }
    __syncthreads();
  }

  const float* bi = bias + (size_t)e * O;
#pragma unroll
  for (int i = 0; i < 4; ++i)
#pragma unroll
    for (int j = 0; j < TO; ++j) acc[i][j] += bi[ol + j];

  if constexpr (LN) {
    float* redS = sA;
    float* redQ = sA + 1024;
    const int grp = wave * 4 + (lane >> 4);
#pragma unroll
    for (int i = 0; i < 4; ++i) {
      float s = 0.f, q = 0.f;
#pragma unroll
      for (int j = 0; j < TO; ++j) { s += acc[i][j]; q += acc[i][j] * acc[i][j]; }
      redS[(bl + i) * 16 + grp] = s;
      redQ[(bl + i) * 16 + grp] = q;
    }
    __syncthreads();
    if (tid < 64) {
      float s = 0.f, q = 0.f;
#pragma unroll
      for (int gi = 0; gi < 16; ++gi) { s += redS[tid * 16 + gi]; q += redQ[tid * 16 + gi]; }
      float mean = s * (1.f / O);
      float var  = q * (1.f / O) - mean * mean;
      mArr[tid] = mean;
      rArr[tid] = rsqrtf(var + 1e-5f);
    }
    __syncthreads();
    const float* gp  = g + (size_t)e * O;
    const float* bbp = bb + (size_t)e * O;
#pragma unroll
    for (int i = 0; i < 4; ++i) {
      float mean = mArr[bl + i], rstd = rArr[bl + i];
#pragma unroll
      for (int j = 0; j < TO; ++j)
        acc[i][j] = (acc[i][j] - mean) * rstd * gp[ol + j] + bbp[ol + j];
    }
  }
  if constexpr (RELU) {
#pragma unroll
    for (int i = 0; i < 4; ++i)
#pragma unroll
      for (int j = 0; j < TO; ++j) acc[i][j] = fmaxf(acc[i][j], 0.f);
  }
#pragma unroll
  for (int i = 0; i < 4; ++i) {
    float* op = out + ((size_t)e * 512 + b0g + bl + i) * O + ol;
#pragma unroll
    for (int j4 = 0; j4 < TO; j4 += 4)
      *(float4*)(op + j4) = make_float4(acc[i][j4], acc[i][j4 + 1], acc[i][j4 + 2], acc[i][j4 + 3]);
  }
}

__global__ void cls_softmax_k(const float* __restrict__ embeds,
                              const float* __restrict__ cw,
                              const float* __restrict__ cbias,
                              float* __restrict__ logits_e,
                              float* __restrict__ conf)
{
  int wv   = (blockIdx.x * 256 + threadIdx.x) >> 6;
  int lane = threadIdx.x & 63;
  int b = wv >> 4, e = wv & 15;
  const float* ep = embeds + ((size_t)e * 512 + b) * 128;
  float e0 = ep[lane], e1 = ep[lane + 64];
  float l[10];
#pragma unroll
  for (int o = 0; o < 10; ++o) {
    const float* wp = cw + ((size_t)e * 10 + o) * 128;
    l[o] = e0 * wp[lane] + e1 * wp[lane + 64];
  }
#pragma unroll
  for (int s = 32; s >= 1; s >>= 1)
#pragma unroll
    for (int o = 0; o < 10; ++o) l[o] += __shfl_xor(l[o], s, 64);
#pragma unroll
  for (int o = 0; o < 10; ++o) l[o] += cbias[e * 10 + o];
  float m = l[0];
#pragma unroll
  for (int o = 1; o < 10; ++o) m = fmaxf(m, l[o]);
  float p[10], sum = 0.f;
#pragma unroll
  for (int o = 0; o < 10; ++o) { p[o] = expf(l[o] - m); sum += p[o]; }
  float inv = 1.f / sum, ent = 0.f;
#pragma unroll
  for (int o = 0; o < 10; ++o) { float pp = p[o] * inv; ent -= pp * logf(pp + 1e-12f); }
  if (lane == 0) {
    conf[b * 16 + e] = -ent;
#pragma unroll
    for (int o = 0; o < 10; ++o) logits_e[((size_t)b * 16 + e) * 10 + o] = l[o];
  }
}

__global__ void gate23_k(const float* __restrict__ g1, const float* __restrict__ w2,
                         const float* __restrict__ b2, const float* __restrict__ w3,
                         const float* __restrict__ b3, float* __restrict__ scores)
{
  int wv   = (blockIdx.x * 256 + threadIdx.x) >> 6;
  int lane = threadIdx.x & 63;
  int b = wv >> 4, e = wv & 15;
  float gv = g1[((size_t)e * 512 + b) * 64 + lane];
  const float* w3p = w3 + e * 32;
  float sc = 0.f;
#pragma unroll
  for (int o = 0; o < 32; ++o) {
    float t = gv * w2[((size_t)e * 32 + o) * 64 + lane];
#pragma unroll
    for (int s = 32; s >= 1; s >>= 1) t += __shfl_xor(t, s, 64);
    float g2v = fmaxf(t + b2[e * 32 + o], 0.f);
    sc = fmaf(g2v, w3p[o], sc);
  }
  if (lane == 0) scores[b * 16 + e] = sc + b3[e];
}

__global__ void routing_k(const float* __restrict__ scores, const float* __restrict__ conf,
                          const float* __restrict__ logits_e, float* __restrict__ out)
{
  __shared__ int t2[512];
  __shared__ int chs[512];
  const int tid = threadIdx.x;

  if (tid < 512) {
    int b = tid;
    float v0 = -3.4e38f, v1 = -3.4e38f;
    int i0 = 0, i1 = 0;
#pragma unroll
    for (int e = 0; e < 16; ++e) {
      float s = scores[b * 16 + e];
      float c = conf[b * 16 + e];
      float v = 0.7f * s + 0.3f * c - 0.125f;
      out[5120 + b * 16 + e] = v;
      if (v > v0) { v1 = v0; i1 = i0; v0 = v; i0 = e; }
      else if (v > v1) { v1 = v; i1 = e; }
    }
    t2[b] = i0 | (i1 << 8);
  }
  __syncthreads();

  if (tid < 64) {
    int lane = tid;
    int cnt = 0;
    int pk[8];
#pragma unroll
    for (int k = 0; k < 8; ++k) pk[k] = t2[k * 64 + lane];
#pragma unroll 1
    for (int k = 0; k < 8; ++k) {
      for (int j = 0; j < 64; ++j) {
        int pair = __shfl(pk[k], j, 64);
        int i0 = pair & 0xff, i1 = (pair >> 8) & 0xff;
        int c0 = __shfl(cnt, i0, 64);
        int c1 = __shfl(cnt, i1, 64);
        int ch = (c0 < 64) ? i0 : ((c1 < 64) ? i1 : ((c0 <= c1) ? i0 : i1));
        cnt += (lane == ch) ? 1 : 0;
        if (lane == 0) chs[k * 64 + j] = ch;
      }
    }
  }
  __syncthreads();

  if (tid < 512) {
    int b = tid;
    int ch = chs[b];
#pragma unroll
    for (int e = 0; e < 16; ++e)
      out[13312 + b * 16 + e] = (e == ch) ? 1.0f : 0.0f;
#pragma unroll
    for (int o = 0; o < 10; ++o)
      out[b * 10 + o] = logits_e[((size_t)b * 16 + ch) * 10 + o];
  }
}

// ============================================================================
extern "C" void kernel_launch(void* const* d_in, const int* in_sizes, int n_in,
                              void* d_out, int out_size, void* d_ws, size_t ws_size,
                              hipStream_t stream) {
  (void)in_sizes; (void)n_in; (void)out_size; (void)ws_size;

  const float* x = (const float*)d_in[0];
  const float *cw[6], *cbv[6], *bsv[6], *bbv[6];
  for (int i = 0; i < 6; ++i) {
    cw[i]  = (const float*)d_in[1 + 4 * i];
    cbv[i] = (const float*)d_in[2 + 4 * i];
    bsv[i] = (const float*)d_in[3 + 4 * i];
    bbv[i] = (const float*)d_in[4 + 4 * i];
  }
  const float* gate_w1  = (const float*)d_in[25];
  const float* gate_b1  = (const float*)d_in[26];
  const float* gate_g1  = (const float*)d_in[27];
  const float* gate_bb1 = (const float*)d_in[28];
  const float* gate_w2  = (const float*)d_in[29];
  const float* gate_b2  = (const float*)d_in[30];
  const float* gate_w3  = (const float*)d_in[31];
  const float* gate_b3  = (const float*)d_in[32];
  const float* exp_w1   = (const float*)d_in[33];
  const float* exp_b1   = (const float*)d_in[34];
  const float* exp_g1   = (const float*)d_in[35];
  const float* exp_bb1  = (const float*)d_in[36];
  const float* exp_w2   = (const float*)d_in[37];
  const float* exp_b2   = (const float*)d_in[38];
  const float* exp_g2   = (const float*)d_in[39];
  const float* exp_bb2  = (const float*)d_in[40];
  const float* exp_w3   = (const float*)d_in[41];
  const float* exp_b3   = (const float*)d_in[42];
  const float* cls_w    = (const float*)d_in[43];
  const float* cls_b    = (const float*)d_in[44];

  char* wsb = (char*)d_ws;
  const size_t off_wt1t = 0;
  const size_t off_whi  = 6912;
  const size_t off_wlo  = 2292480;
  const size_t off_Phi  = 4578048;
  const size_t off_Plo  = 71687168;
  const size_t off_Qhi  = 138796288;
  const size_t off_Qlo  = 155573760;
  const size_t off_feats= 172351232;
  const size_t off_h1   = 138796288 + 512;
  const size_t off_h2   = off_h1 + 8388608;
  const size_t off_emb  = off_h2 + 4194304;
  const size_t off_g1   = off_emb + 4194304;
  const size_t off_lg   = off_g1 + 2097152;
  const size_t off_conf = off_lg + 327680;
  const size_t off_sc   = off_conf + 32768;

  float* wt1t = (float*)(wsb + off_wt1t);
  h16* whi = (h16*)(wsb + off_whi);
  h16* wlo = (h16*)(wsb + off_wlo);
  h16* Phi = (h16*)(wsb + off_Phi);
  h16* Plo = (h16*)(wsb + off_Plo);
  h16* Qhi = (h16*)(wsb + off_Qhi);
  h16* Qlo = (h16*)(wsb + off_Qlo);
  float* feats = (float*)(wsb + off_feats);
  float* h1 = (float*)(wsb + off_h1);
  float* h2 = (float*)(wsb + off_h2);
  float* emb = (float*)(wsb + off_emb);
  float* g1 = (float*)(wsb + off_g1);
  float* lg = (float*)(wsb + off_lg);
  float* conf = (float*)(wsb + off_conf);
  float* sc = (float*)(wsb + off_sc);

  const size_t wo2 = 0;
  const size_t wo3 = 36864;
  const size_t wo4 = 110592;
  const size_t wo5 = 258048;
  const size_t wo6 = 552960;

  // ---- fused prep (pads + wt1 transpose + all weight splits) ----
  prep_all_k<<<4471, 256, 0, stream>>>(cw[0], cw[1], cw[2], cw[3], cw[4], cw[5],
                                       wt1t, whi, wlo, Phi, Plo, Qhi, Qlo);

  // ---- trunk ----
  conv1_k<<<512, 256, 0, stream>>>(x, wt1t, cbv[0], bsv[0], bbv[0], Phi, Plo);
  // <H, W, CIN, COUT, MT, POOL, OCC>
  conv_mfma<32, 32, 64, 64, 2, 1, 3><<<dim3(512, 4, 1), 256, 0, stream>>>(
      Phi, Plo, whi + wo2, cbv[1], bsv[1], bbv[1], Qhi, Qlo, nullptr);
  conv_mfma<16, 16, 64, 128, 2, 0, 3><<<dim3(512, 1, 2), 256, 0, stream>>>(
      Qhi, Qlo, whi + wo3, cbv[2], bsv[2], bbv[2], Phi, Plo, nullptr);
  conv_mfma<16, 16, 128, 128, 2, 1, 3><<<dim3(512, 1, 2), 256, 0, stream>>>(
      Phi, Plo, whi + wo4, cbv[3], bsv[3], bbv[3], Qhi, Qlo, nullptr);
  conv_mfma<8, 8, 128, 256, 1, 0, 4><<<dim3(256, 1, 4), 256, 0, stream>>>(
      Qhi, Qlo, whi + wo5, cbv[4], bsv[4], bbv[4], Phi, Plo, nullptr);
  conv_mfma<8, 8, 256, 256, 1, 2, 4><<<dim3(256, 1, 4), 256, 0, stream>>>(
      Phi, Plo, whi + wo6, cbv[5], bsv[5], bbv[5], nullptr, nullptr, feats);

  // ---- experts ----
  gemm_head<256, 256, 1, 1><<<dim3(8, 16), 256, 0, stream>>>(
      feats, (size_t)0, exp_w1, exp_b1, exp_g1, exp_bb1, h1);
  gemm_head<128, 256, 1, 1><<<dim3(8, 16), 256, 0, stream>>>(
      h1, (size_t)512 * 256, exp_w2, exp_b2, exp_g2, exp_bb2, h2);
  gemm_head<128, 128, 0, 0><<<dim3(8, 16), 256, 0, stream>>>(
      h2, (size_t)512 * 128, exp_w3, exp_b3, nullptr, nullptr, emb);
  cls_softmax_k<<<2048, 256, 0, stream>>>(emb, cls_w, cls_b, lg, conf);

  // ---- gates ----
  gemm_head<64, 256, 1, 1><<<dim3(8, 16), 256, 0, stream>>>(
      feats, (size_t)0, gate_w1, gate_b1, gate_g1, gate_bb1, g1);
  gate23_k<<<2048, 256, 0, stream>>>(g1, gate_w2, gate_b2, gate_w3, gate_b3, sc);

  // ---- routing + outputs ----
  routing_k<<<1, 512, 0, stream>>>(sc, conf, lg, (float*)d_out);
}

// Round 14
// 787.781 us; speedup vs baseline: 1.1332x; 1.0353x over previous
//
#include <hip/hip_runtime.h>

// ============================================================================
// ImprovedMoE R14 = R13 + single-barrier double-buffered B staging:
//   per ck: load B[ck+1] -> registers, tap/MFMA loop on sBh[buf],
//   ds_write regs -> sBh[buf^1], ONE __syncthreads. (m97-style bounce:
//   keeps tap ds_reads ahead of staging ds_writes in the in-order DS pipe,
//   halves barriers, lets A-prefetch run across ck boundaries.)
// D = (Ah+Al)*Bh (R13 precision scheme, measured absmax 0.0078 PASS).
// ============================================================================

typedef _Float16 h16;
typedef _Float16 half8 __attribute__((ext_vector_type(8)));
typedef float f32x16 __attribute__((ext_vector_type(16)));

__device__ __forceinline__ void split2f(float x, h16& hh, h16& ll) {
  h16 a = (h16)x;
  hh = a;
  ll = (h16)(x - (float)a);
}

// ---- fused prep: zero pads + conv1 wt transpose + conv2..6 weight split ----
// wsplit layout: wh[ck][tap][cob][half][co64][c8]   (hi plane only — R13)
__global__ void prep_all_k(const float* __restrict__ cw1, const float* __restrict__ cw2,
                           const float* __restrict__ cw3, const float* __restrict__ cw4,
                           const float* __restrict__ cw5, const float* __restrict__ cw6,
                           float* __restrict__ wt1t, h16* __restrict__ wh,
                           h16* p0, h16* p1, h16* p2, h16* p3) {
  int idx = blockIdx.x * 256 + threadIdx.x;
  if (idx < 64) {
    h16* p = (idx < 16) ? p0 : (idx < 32) ? p1 : (idx < 48) ? p2 : p3;
    p[idx & 15] = (h16)0.f;
    return;
  }
  idx -= 64;
  if (idx < 1728) {
    int co = idx % 64, r = idx / 64;
    wt1t[idx] = cw1[(size_t)co * 27 + r];
    return;
  }
  idx -= 1728;
  const float* w; int CIN, COUT; size_t off;
  if (idx < 36864)        { w = cw2; CIN = 64;  COUT = 64;  off = 0; }
  else if (idx < 110592)  { w = cw3; CIN = 64;  COUT = 128; off = 36864;  idx -= 36864; }
  else if (idx < 258048)  { w = cw4; CIN = 128; COUT = 128; off = 110592; idx -= 110592; }
  else if (idx < 552960)  { w = cw5; CIN = 128; COUT = 256; off = 258048; idx -= 258048; }
  else if (idx < 1142784) { w = cw6; CIN = 256; COUT = 256; off = 552960; idx -= 552960; }
  else return;
  int KCOB = COUT >> 6;
  int lidx = idx;
  int c8   = idx & 7;
  int t    = idx >> 3;
  int co64 = t & 63;  t >>= 6;
  int half = t & 1;   t >>= 1;
  int cob  = t % KCOB; t /= KCOB;
  int tap  = t % 9;
  int ck   = t / 9;
  int ci = ck * 16 + half * 8 + c8;
  int co = cob * 64 + co64;
  float v = w[((size_t)co * CIN + ci) * 9 + tap];
  wh[off + lidx] = (h16)v;
}

// ---- conv1: 3->64, 32x32, fp32 vector; outputs blocked hi/lo planes (+16) ----
__global__ __launch_bounds__(256) void conv1_k(
    const float* __restrict__ x, const float* __restrict__ wt,
    const float* __restrict__ cb, const float* __restrict__ bns,
    const float* __restrict__ bnb, h16* __restrict__ oh, h16* __restrict__ ol)
{
  __shared__ float sx[3 * 34 * 34];
  const int tid = threadIdx.x;
  const int img = blockIdx.x;
  for (int idx = tid; idx < 3 * 34 * 34; idx += 256) {
    int xx = idx % 34;
    int t  = idx / 34;
    int rr = t % 34;
    int c  = t / 34;
    int gr = rr - 1, gx = xx - 1;
    float v = 0.f;
    if (gr >= 0 && gr < 32 && gx >= 0 && gx < 32)
      v = x[((size_t)(img * 3 + c) * 32 + gr) * 32 + gx];
    sx[(c * 34 + rr) * 34 + xx] = v;
  }
  __syncthreads();
#pragma unroll 1
  for (int k = 0; k < 4; ++k) {
    int px = k * 256 + tid;
    int yy = px >> 5, xx = px & 31;
    float in27[27];
#pragma unroll
    for (int c = 0; c < 3; ++c)
#pragma unroll
      for (int dy = 0; dy < 3; ++dy)
#pragma unroll
        for (int dx = 0; dx < 3; ++dx)
          in27[c * 9 + dy * 3 + dx] = sx[(c * 34 + yy + dy) * 34 + xx + dx];
#pragma unroll 1
    for (int cbk = 0; cbk < 4; ++cbk) {
      h16 hb[16], lb[16];
#pragma unroll
      for (int j = 0; j < 16; ++j) {
        int co = cbk * 16 + j;
        float acc = 0.f;
#pragma unroll
        for (int t = 0; t < 27; ++t) acc = fmaf(in27[t], wt[t * 64 + co], acc);
        float s = bns[co];
        float yv = fmaxf(fmaf(acc + cb[co], s, bnb[co]), 0.f);
        split2f(yv, hb[j], lb[j]);
      }
      size_t o = 16 + ((size_t)(img * 4 + cbk) * 1024 + px) * 16;
      *(half8*)&oh[o]     = *(half8*)&hb[0];
      *(half8*)&oh[o + 8] = *(half8*)&hb[8];
      *(half8*)&ol[o]     = *(half8*)&lb[0];
      *(half8*)&ol[o + 8] = *(half8*)&lb[8];
    }
  }
}

// ---------------------------------------------------------------------------
// MFMA conv: 3x3 SAME, tap-decomposed implicit GEMM. D = (Ah+Al)*Bh.
// Double-buffered B in LDS, ONE barrier/ck, register-bounce staging.
// A hi/lo direct-from-global with PF-deep prefetch; zero-pad sentinel halo.
// 4 waves/block on one 64-co block; each wave: MT m-tiles x 2 n-tiles.
// ---------------------------------------------------------------------------
template<int H, int W, int CIN, int COUT, int MT, int POOL, int OCC>
__global__ __launch_bounds__(256, OCC) void conv_mfma(
    const h16* __restrict__ Ah, const h16* __restrict__ Al,
    const h16* __restrict__ Wh,
    const float* __restrict__ cb, const float* __restrict__ bns,
    const float* __restrict__ bnb,
    h16* __restrict__ Oh, h16* __restrict__ Ol, float* __restrict__ feats)
{
  constexpr int TPI  = (H * W) / 32;
  constexpr int RPT  = 32 / W;
  constexpr int IPB  = (4 * MT * 32 >= H * W) ? (4 * MT * 32) / (H * W) : 1;
  constexpr int KC   = CIN / 16;
  constexpr int HW   = H * W;
  constexpr int KCO  = COUT / 16;
  constexpr int KCOB = COUT / 64;
  constexpr int LOGW = (W == 32) ? 5 : (W == 16) ? 4 : 3;
  constexpr int PF   = (MT == 1) ? 3 : 2;   // A-prefetch depth (taps in flight)

  __shared__ h16 sBh[2][9 * 2 * 64 * 8];   // 2 x 18.4 KB, [tap][half][co64][c8]
  __shared__ float sRed[(POOL == 2 && MT == 1) ? 256 : 1];

  const int tid  = threadIdx.x;
  const int lane = tid & 63;
  const int wave = tid >> 6;
  const int half = lane >> 5;
  const int col  = lane & 31;
  const int cob  = blockIdx.z;
  const int co0  = cob * 64;

  int aoff[MT], ty[MT], tx[MT], img_t[MT], rw0[MT];
#pragma unroll
  for (int t = 0; t < MT; ++t) {
    int gt   = blockIdx.y * (4 * MT) + wave * MT + t;
    int img  = blockIdx.x * IPB + gt / TPI;
    int row0 = (gt % TPI) * RPT;
    int y = row0 + (col >> LOGW);
    int x = col & (W - 1);
    img_t[t] = img; rw0[t] = row0; ty[t] = y; tx[t] = x;
    aoff[t] = 16 + ((img * KC) * HW + y * W + x) * 16 + half * 8;
  }

  f32x16 acc[MT][2];
#pragma unroll
  for (int t = 0; t < MT; ++t)
#pragma unroll
    for (int n = 0; n < 2; ++n)
#pragma unroll
      for (int i = 0; i < 16; ++i) acc[t][n][i] = 0.f;

  // ---- stage B[0] into buffer 0 ----
#pragma unroll
  for (int i = 0; i < 5; ++i) {
    int id = tid + i * 256;
    if (id < 1152) {
      int src = ((0 * 9 + (id >> 7)) * KCOB + cob) * 1024 + (id & 127) * 8;
      *(half8*)&sBh[0][id * 8] = *(const half8*)(Wh + src);
    }
  }
  __syncthreads();

  int buf = 0;
#pragma unroll 1
  for (int ck = 0; ck < KC; ++ck) {
    // ---- issue next ck's B loads into registers (no LDS op yet) ----
    half8 stg[5];
    const bool have_next = (ck + 1 < KC);
    if (have_next) {
#pragma unroll
      for (int i = 0; i < 5; ++i) {
        int id = tid + i * 256;
        if (id < 1152) {
          int src = (((ck + 1) * 9 + (id >> 7)) * KCOB + cob) * 1024 + (id & 127) * 8;
          stg[i] = *(const half8*)(Wh + src);
        }
      }
    }

    const int ckoA = ck * (HW * 16);
    const h16* bB = sBh[buf];

    // ---- A prefetch pipeline: prologue loads taps 0..PF-1 ----
    half8 pah[PF][MT], pal[PF][MT];
#pragma unroll
    for (int pt = 0; pt < PF; ++pt) {
      const int dy = pt / 3 - 1, dx = pt % 3 - 1;
      const int ashift = (dy * W + dx) * 16;
#pragma unroll
      for (int t = 0; t < MT; ++t) {
        bool v = ((unsigned)(ty[t] + dy) < (unsigned)H) &&
                 ((unsigned)(tx[t] + dx) < (unsigned)W);
        int ai = v ? (aoff[t] + ckoA + ashift) : (half * 8);
        pah[pt][t] = *(const half8*)(Ah + ai);
        pal[pt][t] = *(const half8*)(Al + ai);
      }
    }

#pragma unroll
    for (int tap = 0; tap < 9; ++tap) {
      const int bufr = tap % PF;
      half8 bh[2];
#pragma unroll
      for (int n = 0; n < 2; ++n) {
        int bi = ((tap * 2 + half) * 64 + n * 32 + col) * 8;
        bh[n] = *(const half8*)&bB[bi];
      }
      half8 cah[MT], cal[MT];
#pragma unroll
      for (int t = 0; t < MT; ++t) { cah[t] = pah[bufr][t]; cal[t] = pal[bufr][t]; }
      if (tap + PF < 9) {
        const int pt = tap + PF;
        const int dy = pt / 3 - 1, dx = pt % 3 - 1;
        const int ashift = (dy * W + dx) * 16;
#pragma unroll
        for (int t = 0; t < MT; ++t) {
          bool v = ((unsigned)(ty[t] + dy) < (unsigned)H) &&
                   ((unsigned)(tx[t] + dx) < (unsigned)W);
          int ai = v ? (aoff[t] + ckoA + ashift) : (half * 8);
          pah[bufr][t] = *(const half8*)(Ah + ai);
          pal[bufr][t] = *(const half8*)(Al + ai);
        }
      }
#pragma unroll
      for (int t = 0; t < MT; ++t)
#pragma unroll
        for (int n = 0; n < 2; ++n) {
          acc[t][n] = __builtin_amdgcn_mfma_f32_32x32x16_f16(cah[t], bh[n], acc[t][n], 0, 0, 0);
          acc[t][n] = __builtin_amdgcn_mfma_f32_32x32x16_f16(cal[t], bh[n], acc[t][n], 0, 0, 0);
        }
    }

    // ---- commit staged B into the other buffer, one barrier ----
    if (have_next) {
#pragma unroll
      for (int i = 0; i < 5; ++i) {
        int id = tid + i * 256;
        if (id < 1152)
          *(half8*)&sBh[buf ^ 1][id * 8] = stg[i];
      }
    }
    __syncthreads();
    buf ^= 1;
  }

  // ---- epilogue: y = acc*s + (cb*s+bb), relu, pool, split-store (blocked+16) ----
#pragma unroll
  for (int n = 0; n < 2; ++n) {
    const int co = co0 + n * 32 + col;
    const float es = bns[co];
    const float eb = fmaf(cb[co], es, bnb[co]);
    const int cko = co >> 4, c16 = co & 15;

    if constexpr (POOL == 0) {
#pragma unroll
      for (int t = 0; t < MT; ++t) {
#pragma unroll
        for (int r = 0; r < 16; ++r) {
          float v = fmaxf(fmaf(acc[t][n][r], es, eb), 0.f);
          int m = (r & 3) + 4 * half + 8 * (r >> 2);
          int y = rw0[t] + (m >> LOGW);
          int x = m & (W - 1);
          size_t oi = 16 + ((size_t)(img_t[t] * KCO + cko) * HW + y * W + x) * 16 + c16;
          h16 hh, ll; split2f(v, hh, ll);
          Oh[oi] = hh; Ol[oi] = ll;
        }
      }
    } else if constexpr (POOL == 1 && RPT == 1) {   // conv2: y-pair across tiles
      constexpr int HWq = (H / 2) * (W / 2);
#pragma unroll
      for (int tp = 0; tp < MT / 2; ++tp) {
        const int t0 = 2 * tp, t1 = 2 * tp + 1;
        const int yq = rw0[t0] >> 1;
#pragma unroll
        for (int r = 0; r < 16; r += 2) {
          float v00 = fmaxf(fmaf(acc[t0][n][r],     es, eb), 0.f);
          float v01 = fmaxf(fmaf(acc[t0][n][r + 1], es, eb), 0.f);
          float v10 = fmaxf(fmaf(acc[t1][n][r],     es, eb), 0.f);
          float v11 = fmaxf(fmaf(acc[t1][n][r + 1], es, eb), 0.f);
          float mv = fmaxf(fmaxf(v00, v01), fmaxf(v10, v11));
          int xq = ((r & 3) >> 1) + 2 * half + 4 * (r >> 2);
          size_t oi = 16 + ((size_t)(img_t[t0] * KCO + cko) * HWq + yq * (W / 2) + xq) * 16 + c16;
          h16 hh, ll; split2f(mv, hh, ll);
          Oh[oi] = hh; Ol[oi] = ll;
        }
      }
    } else if constexpr (POOL == 1) {               // conv4 (RPT==2): intra-reg
      constexpr int HWq = (H / 2) * (W / 2);
#pragma unroll
      for (int t = 0; t < MT; ++t) {
        const int yq = rw0[t] >> 1;
#pragma unroll
        for (int r = 0; r < 8; r += 2) {
          float v00 = fmaxf(fmaf(acc[t][n][r],     es, eb), 0.f);
          float v01 = fmaxf(fmaf(acc[t][n][r + 1], es, eb), 0.f);
          float v10 = fmaxf(fmaf(acc[t][n][r + 8], es, eb), 0.f);
          float v11 = fmaxf(fmaf(acc[t][n][r + 9], es, eb), 0.f);
          float mv = fmaxf(fmaxf(v00, v01), fmaxf(v10, v11));
          int xq = ((r & 3) >> 1) + 2 * half + 4 * (r >> 2);
          size_t oi = 16 + ((size_t)(img_t[t] * KCO + cko) * HWq + yq * (W / 2) + xq) * 16 + c16;
          h16 hh, ll; split2f(mv, hh, ll);
          Oh[oi] = hh; Ol[oi] = ll;
        }
      }
    } else if constexpr (POOL == 2 && MT == 1) {    // conv6: 2 waves share an image
      float s = 0.f;
#pragma unroll
      for (int r = 0; r < 16; ++r)
        s += fmaxf(fmaf(acc[0][n][r], es, eb), 0.f);
      s += __shfl_xor(s, 32, 64);                   // full 32-px tile sum
      if (half == 0) sRed[wave * 64 + n * 32 + col] = s;
    } else if constexpr (POOL == 2) {               // MT==2: full image per wave
      float s = 0.f;
#pragma unroll
      for (int t = 0; t < MT; ++t)
#pragma unroll
        for (int r = 0; r < 16; ++r)
          s += fmaxf(fmaf(acc[t][n][r], es, eb), 0.f);
      s += __shfl_xor(s, 32, 64);
      if (half == 0) feats[(size_t)img_t[0] * 256 + co] = s * (1.f / 64.f);
    }
  }

  if constexpr (POOL == 2 && MT == 1) {
    __syncthreads();
    if (tid < 128) {
      int li = tid >> 6, co_l = tid & 63;
      float s = sRed[(li * 2) * 64 + co_l] + sRed[(li * 2 + 1) * 64 + co_l];
      feats[(size_t)(blockIdx.x * 2 + li) * 256 + co0 + co_l] = s * (1.f / 64.f);
    }
  }
}

// ---------------------------------------------------------------------------
// Batched head GEMM (R1, verified).
// ---------------------------------------------------------------------------
template<int O, int K, int LN, int RELU>
__global__ __launch_bounds__(256, 4) void gemm_head(
    const float* __restrict__ A, size_t aStrideE,
    const float* __restrict__ Wm, const float* __restrict__ bias,
    const float* __restrict__ g, const float* __restrict__ bb,
    float* __restrict__ out)
{
  constexpr int KC  = (O >= 256) ? 32 : 64;
  constexpr int WST = O + 4;
  constexpr int TO  = O / 16;
  __shared__ float sA[KC * 68];
  __shared__ float sW[KC * WST];
  __shared__ float mArr[64], rArr[64];

  const int tid  = threadIdx.x;
  const int lane = tid & 63;
  const int wave = tid >> 6;
  const int e    = blockIdx.y;
  const int b0g  = blockIdx.x * 64;
  const int bl   = (lane & 15) * 4;
  const int ol   = wave * (O / 4) + (lane >> 4) * TO;

  const float* Ae = A + (size_t)e * aStrideE;
  const float* We = Wm + (size_t)e * O * K;

  float acc[4][TO];
#pragma unroll
  for (int i = 0; i < 4; ++i)
#pragma unroll
    for (int j = 0; j < TO; ++j) acc[i][j] = 0.f;

  for (int k0 = 0; k0 < K; k0 += KC) {
    for (int idx = tid; idx < 64 * KC; idx += 256) {
      int kk = idx % KC, bb_ = idx / KC;
      sA[kk * 68 + bb_] = Ae[(size_t)(b0g + bb_) * K + k0 + kk];
    }
    for (int idx = tid; idx < O * KC; idx += 256) {
      int kk = idx % KC, oo = idx / KC;
      sW[kk * WST + oo] = We[(size_t)oo * K + k0 + kk];
    }
    __syncthreads();
#pragma unroll 4
    for (int kk = 0; kk < KC; ++kk) {
      float4 av = *(const float4*)&sA[kk * 68 + bl];
      float a4[4] = {av.x, av.y, av.z, av.w};
#pragma unroll
      for (int j4 = 0; j4 < TO; j4 += 4) {
        float4 wv = *(const float4*)&sW[kk * WST + ol + j4];
        float w4[4] = {wv.x, wv.y, wv.z, wv.w};
#pragma unroll
        for (int i = 0; i < 4; ++i)
#pragma unroll
          for (int jj = 0; jj < 4; ++jj)
            acc[i][j4 + jj] = fmaf(a4[i], w4[jj], acc[i][j4 + jj]);
      }
    }
    __syncthreads();
  }

  const float* bi = bias + (size_t)e * O;
#pragma unroll
  for (int i = 0; i < 4; ++i)
#pragma unroll
    for (int j = 0; j < TO; ++j) acc[i][j] += bi[ol + j];

  if constexpr (LN) {
    float* redS = sA;
    float* redQ = sA + 1024;
    const int grp = wave * 4 + (lane >> 4);
#pragma unroll
    for (int i = 0; i < 4; ++i) {
      float s = 0.f, q = 0.f;
#pragma unroll
      for (int j = 0; j < TO; ++j) { s += acc[i][j]; q += acc[i][j] * acc[i][j]; }
      redS[(bl + i) * 16 + grp] = s;
      redQ[(bl + i) * 16 + grp] = q;
    }
    __syncthreads();
    if (tid < 64) {
      float s = 0.f, q = 0.f;
#pragma unroll
      for (int gi = 0; gi < 16; ++gi) { s += redS[tid * 16 + gi]; q += redQ[tid * 16 + gi]; }
      float mean = s * (1.f / O);
      float var  = q * (1.f / O) - mean * mean;
      mArr[tid] = mean;
      rArr[tid] = rsqrtf(var + 1e-5f);
    }
    __syncthreads();
    const float* gp  = g + (size_t)e * O;
    const float* bbp = bb + (size_t)e * O;
#pragma unroll
    for (int i = 0; i < 4; ++i) {
      float mean = mArr[bl + i], rstd = rArr[bl + i];
#pragma unroll
      for (int j = 0; j < TO; ++j)
        acc[i][j] = (acc[i][j] - mean) * rstd * gp[ol + j] + bbp[ol + j];
    }
  }
  if constexpr (RELU) {
#pragma unroll
    for (int i = 0; i < 4; ++i)
#pragma unroll
      for (int j = 0; j < TO; ++j) acc[i][j] = fmaxf(acc[i][j], 0.f);
  }
#pragma unroll
  for (int i = 0; i < 4; ++i) {
    float* op = out + ((size_t)e * 512 + b0g + bl + i) * O + ol;
#pragma unroll
    for (int j4 = 0; j4 < TO; j4 += 4)
      *(float4*)(op + j4) = make_float4(acc[i][j4], acc[i][j4 + 1], acc[i][j4 + 2], acc[i][j4 + 3]);
  }
}

__global__ void cls_softmax_k(const float* __restrict__ embeds,
                              const float* __restrict__ cw,
                              const float* __restrict__ cbias,
                              float* __restrict__ logits_e,
                              float* __restrict__ conf)
{
  int wv   = (blockIdx.x * 256 + threadIdx.x) >> 6;
  int lane = threadIdx.x & 63;
  int b = wv >> 4, e = wv & 15;
  const float* ep = embeds + ((size_t)e * 512 + b) * 128;
  float e0 = ep[lane], e1 = ep[lane + 64];
  float l[10];
#pragma unroll
  for (int o = 0; o < 10; ++o) {
    const float* wp = cw + ((size_t)e * 10 + o) * 128;
    l[o] = e0 * wp[lane] + e1 * wp[lane + 64];
  }
#pragma unroll
  for (int s = 32; s >= 1; s >>= 1)
#pragma unroll
    for (int o = 0; o < 10; ++o) l[o] += __shfl_xor(l[o], s, 64);
#pragma unroll
  for (int o = 0; o < 10; ++o) l[o] += cbias[e * 10 + o];
  float m = l[0];
#pragma unroll
  for (int o = 1; o < 10; ++o) m = fmaxf(m, l[o]);
  float p[10], sum = 0.f;
#pragma unroll
  for (int o = 0; o < 10; ++o) { p[o] = expf(l[o] - m); sum += p[o]; }
  float inv = 1.f / sum, ent = 0.f;
#pragma unroll
  for (int o = 0; o < 10; ++o) { float pp = p[o] * inv; ent -= pp * logf(pp + 1e-12f); }
  if (lane == 0) {
    conf[b * 16 + e] = -ent;
#pragma unroll
    for (int o = 0; o < 10; ++o) logits_e[((size_t)b * 16 + e) * 10 + o] = l[o];
  }
}

__global__ void gate23_k(const float* __restrict__ g1, const float* __restrict__ w2,
                         const float* __restrict__ b2, const float* __restrict__ w3,
                         const float* __restrict__ b3, float* __restrict__ scores)
{
  int wv   = (blockIdx.x * 256 + threadIdx.x) >> 6;
  int lane = threadIdx.x & 63;
  int b = wv >> 4, e = wv & 15;
  float gv = g1[((size_t)e * 512 + b) * 64 + lane];
  const float* w3p = w3 + e * 32;
  float sc = 0.f;
#pragma unroll
  for (int o = 0; o < 32; ++o) {
    float t = gv * w2[((size_t)e * 32 + o) * 64 + lane];
#pragma unroll
    for (int s = 32; s >= 1; s >>= 1) t += __shfl_xor(t, s, 64);
    float g2v = fmaxf(t + b2[e * 32 + o], 0.f);
    sc = fmaf(g2v, w3p[o], sc);
  }
  if (lane == 0) scores[b * 16 + e] = sc + b3[e];
}

__global__ void routing_k(const float* __restrict__ scores, const float* __restrict__ conf,
                          const float* __restrict__ logits_e, float* __restrict__ out)
{
  __shared__ int t2[512];
  __shared__ int chs[512];
  const int tid = threadIdx.x;

  if (tid < 512) {
    int b = tid;
    float v0 = -3.4e38f, v1 = -3.4e38f;
    int i0 = 0, i1 = 0;
#pragma unroll
    for (int e = 0; e < 16; ++e) {
      float s = scores[b * 16 + e];
      float c = conf[b * 16 + e];
      float v = 0.7f * s + 0.3f * c - 0.125f;
      out[5120 + b * 16 + e] = v;
      if (v > v0) { v1 = v0; i1 = i0; v0 = v; i0 = e; }
      else if (v > v1) { v1 = v; i1 = e; }
    }
    t2[b] = i0 | (i1 << 8);
  }
  __syncthreads();

  if (tid < 64) {
    int lane = tid;
    int cnt = 0;
    int pk[8];
#pragma unroll
    for (int k = 0; k < 8; ++k) pk[k] = t2[k * 64 + lane];
#pragma unroll 1
    for (int k = 0; k < 8; ++k) {
      for (int j = 0; j < 64; ++j) {
        int pair = __shfl(pk[k], j, 64);
        int i0 = pair & 0xff, i1 = (pair >> 8) & 0xff;
        int c0 = __shfl(cnt, i0, 64);
        int c1 = __shfl(cnt, i1, 64);
        int ch = (c0 < 64) ? i0 : ((c1 < 64) ? i1 : ((c0 <= c1) ? i0 : i1));
        cnt += (lane == ch) ? 1 : 0;
        if (lane == 0) chs[k * 64 + j] = ch;
      }
    }
  }
  __syncthreads();

  if (tid < 512) {
    int b = tid;
    int ch = chs[b];
#pragma unroll
    for (int e = 0; e < 16; ++e)
      out[13312 + b * 16 + e] = (e == ch) ? 1.0f : 0.0f;
#pragma unroll
    for (int o = 0; o < 10; ++o)
      out[b * 10 + o] = logits_e[((size_t)b * 16 + ch) * 10 + o];
  }
}

// ============================================================================
extern "C" void kernel_launch(void* const* d_in, const int* in_sizes, int n_in,
                              void* d_out, int out_size, void* d_ws, size_t ws_size,
                              hipStream_t stream) {
  (void)in_sizes; (void)n_in; (void)out_size; (void)ws_size;

  const float* x = (const float*)d_in[0];
  const float *cw[6], *cbv[6], *bsv[6], *bbv[6];
  for (int i = 0; i < 6; ++i) {
    cw[i]  = (const float*)d_in[1 + 4 * i];
    cbv[i] = (const float*)d_in[2 + 4 * i];
    bsv[i] = (const float*)d_in[3 + 4 * i];
    bbv[i] = (const float*)d_in[4 + 4 * i];
  }
  const float* gate_w1  = (const float*)d_in[25];
  const float* gate_b1  = (const float*)d_in[26];
  const float* gate_g1  = (const float*)d_in[27];
  const float* gate_bb1 = (const float*)d_in[28];
  const float* gate_w2  = (const float*)d_in[29];
  const float* gate_b2  = (const float*)d_in[30];
  const float* gate_w3  = (const float*)d_in[31];
  const float* gate_b3  = (const float*)d_in[32];
  const float* exp_w1   = (const float*)d_in[33];
  const float* exp_b1   = (const float*)d_in[34];
  const float* exp_g1   = (const float*)d_in[35];
  const float* exp_bb1  = (const float*)d_in[36];
  const float* exp_w2   = (const float*)d_in[37];
  const float* exp_b2   = (const float*)d_in[38];
  const float* exp_g2   = (const float*)d_in[39];
  const float* exp_bb2  = (const float*)d_in[40];
  const float* exp_w3   = (const float*)d_in[41];
  const float* exp_b3   = (const float*)d_in[42];
  const float* cls_w    = (const float*)d_in[43];
  const float* cls_b    = (const float*)d_in[44];

  char* wsb = (char*)d_ws;
  const size_t off_wt1t = 0;
  const size_t off_whi  = 6912;
  const size_t off_Phi  = 4578048;
  const size_t off_Plo  = 71687168;
  const size_t off_Qhi  = 138796288;
  const size_t off_Qlo  = 155573760;
  const size_t off_feats= 172351232;
  const size_t off_h1   = 138796288 + 512;
  const size_t off_h2   = off_h1 + 8388608;
  const size_t off_emb  = off_h2 + 4194304;
  const size_t off_g1   = off_emb + 4194304;
  const size_t off_lg   = off_g1 + 2097152;
  const size_t off_conf = off_lg + 327680;
  const size_t off_sc   = off_conf + 32768;

  float* wt1t = (float*)(wsb + off_wt1t);
  h16* whi = (h16*)(wsb + off_whi);
  h16* Phi = (h16*)(wsb + off_Phi);
  h16* Plo = (h16*)(wsb + off_Plo);
  h16* Qhi = (h16*)(wsb + off_Qhi);
  h16* Qlo = (h16*)(wsb + off_Qlo);
  float* feats = (float*)(wsb + off_feats);
  float* h1 = (float*)(wsb + off_h1);
  float* h2 = (float*)(wsb + off_h2);
  float* emb = (float*)(wsb + off_emb);
  float* g1 = (float*)(wsb + off_g1);
  float* lg = (float*)(wsb + off_lg);
  float* conf = (float*)(wsb + off_conf);
  float* sc = (float*)(wsb + off_sc);

  const size_t wo2 = 0;
  const size_t wo3 = 36864;
  const size_t wo4 = 110592;
  const size_t wo5 = 258048;
  const size_t wo6 = 552960;

  // ---- fused prep (pads + wt1 transpose + all weight splits) ----
  prep_all_k<<<4471, 256, 0, stream>>>(cw[0], cw[1], cw[2], cw[3], cw[4], cw[5],
                                       wt1t, whi, Phi, Plo, Qhi, Qlo);

  // ---- trunk ----
  conv1_k<<<512, 256, 0, stream>>>(x, wt1t, cbv[0], bsv[0], bbv[0], Phi, Plo);
  // <H, W, CIN, COUT, MT, POOL, OCC>
  conv_mfma<32, 32, 64, 64, 2, 1, 3><<<dim3(512, 4, 1), 256, 0, stream>>>(
      Phi, Plo, whi + wo2, cbv[1], bsv[1], bbv[1], Qhi, Qlo, nullptr);
  conv_mfma<16, 16, 64, 128, 2, 0, 3><<<dim3(512, 1, 2), 256, 0, stream>>>(
      Qhi, Qlo, whi + wo3, cbv[2], bsv[2], bbv[2], Phi, Plo, nullptr);
  conv_mfma<16, 16, 128, 128, 2, 1, 3><<<dim3(512, 1, 2), 256, 0, stream>>>(
      Phi, Plo, whi + wo4, cbv[3], bsv[3], bbv[3], Qhi, Qlo, nullptr);
  conv_mfma<8, 8, 128, 256, 1, 0, 4><<<dim3(256, 1, 4), 256, 0, stream>>>(
      Qhi, Qlo, whi + wo5, cbv[4], bsv[4], bbv[4], Phi, Plo, nullptr);
  conv_mfma<8, 8, 256, 256, 1, 2, 4><<<dim3(256, 1, 4), 256, 0, stream>>>(
      Phi, Plo, whi + wo6, cbv[5], bsv[5], bbv[5], nullptr, nullptr, feats);

  // ---- experts ----
  gemm_head<256, 256, 1, 1><<<dim3(8, 16), 256, 0, stream>>>(
      feats, (size_t)0, exp_w1, exp_b1, exp_g1, exp_bb1, h1);
  gemm_head<128, 256, 1, 1><<<dim3(8, 16), 256, 0, stream>>>(
      h1, (size_t)512 * 256, exp_w2, exp_b2, exp_g2, exp_bb2, h2);
  gemm_head<128, 128, 0, 0><<<dim3(8, 16), 256, 0, stream>>>(
      h2, (size_t)512 * 128, exp_w3, exp_b3, nullptr, nullptr, emb);
  cls_softmax_k<<<2048, 256, 0, stream>>>(emb, cls_w, cls_b, lg, conf);

  // ---- gates ----
  gemm_head<64, 256, 1, 1><<<dim3(8, 16), 256, 0, stream>>>(
      feats, (size_t)0, gate_w1, gate_b1, gate_g1, gate_bb1, g1);
  gate23_k<<<2048, 256, 0, stream>>>(g1, gate_w2, gate_b2, gate_w3, gate_b3, sc);

  // ---- routing + outputs ----
  routing_k<<<1, 512, 0, stream>>>(sc, conf, lg, (float*)d_out);
}

// Round 16
// 786.979 us; speedup vs baseline: 1.1343x; 1.0010x over previous
//
#include <hip/hip_runtime.h>

// ============================================================================
// ImprovedMoE R16 = exact revert to R14 (verified 787.8 us, absmax 0.0078).
// R15 (fp16 A) flipped routing (absmax 2.66) -> precision floor established:
//   activations need fp32-grade (hi+lo fp16 planes); weights tolerate fp16.
// D = (Ah+Al)*Bh; single-barrier double-buffered B in LDS; PF A-prefetch.
// ============================================================================

typedef _Float16 h16;
typedef _Float16 half8 __attribute__((ext_vector_type(8)));
typedef float f32x16 __attribute__((ext_vector_type(16)));

__device__ __forceinline__ void split2f(float x, h16& hh, h16& ll) {
  h16 a = (h16)x;
  hh = a;
  ll = (h16)(x - (float)a);
}

// ---- fused prep: zero pads + conv1 wt transpose + conv2..6 weight split ----
// wsplit layout: wh[ck][tap][cob][half][co64][c8]   (hi plane only)
__global__ void prep_all_k(const float* __restrict__ cw1, const float* __restrict__ cw2,
                           const float* __restrict__ cw3, const float* __restrict__ cw4,
                           const float* __restrict__ cw5, const float* __restrict__ cw6,
                           float* __restrict__ wt1t, h16* __restrict__ wh,
                           h16* p0, h16* p1, h16* p2, h16* p3) {
  int idx = blockIdx.x * 256 + threadIdx.x;
  if (idx < 64) {
    h16* p = (idx < 16) ? p0 : (idx < 32) ? p1 : (idx < 48) ? p2 : p3;
    p[idx & 15] = (h16)0.f;
    return;
  }
  idx -= 64;
  if (idx < 1728) {
    int co = idx % 64, r = idx / 64;
    wt1t[idx] = cw1[(size_t)co * 27 + r];
    return;
  }
  idx -= 1728;
  const float* w; int CIN, COUT; size_t off;
  if (idx < 36864)        { w = cw2; CIN = 64;  COUT = 64;  off = 0; }
  else if (idx < 110592)  { w = cw3; CIN = 64;  COUT = 128; off = 36864;  idx -= 36864; }
  else if (idx < 258048)  { w = cw4; CIN = 128; COUT = 128; off = 110592; idx -= 110592; }
  else if (idx < 552960)  { w = cw5; CIN = 128; COUT = 256; off = 258048; idx -= 258048; }
  else if (idx < 1142784) { w = cw6; CIN = 256; COUT = 256; off = 552960; idx -= 552960; }
  else return;
  int KCOB = COUT >> 6;
  int lidx = idx;
  int c8   = idx & 7;
  int t    = idx >> 3;
  int co64 = t & 63;  t >>= 6;
  int half = t & 1;   t >>= 1;
  int cob  = t % KCOB; t /= KCOB;
  int tap  = t % 9;
  int ck   = t / 9;
  int ci = ck * 16 + half * 8 + c8;
  int co = cob * 64 + co64;
  float v = w[((size_t)co * CIN + ci) * 9 + tap];
  wh[off + lidx] = (h16)v;
}

// ---- conv1: 3->64, 32x32, fp32 vector; outputs blocked hi/lo planes (+16) ----
__global__ __launch_bounds__(256) void conv1_k(
    const float* __restrict__ x, const float* __restrict__ wt,
    const float* __restrict__ cb, const float* __restrict__ bns,
    const float* __restrict__ bnb, h16* __restrict__ oh, h16* __restrict__ ol)
{
  __shared__ float sx[3 * 34 * 34];
  const int tid = threadIdx.x;
  const int img = blockIdx.x;
  for (int idx = tid; idx < 3 * 34 * 34; idx += 256) {
    int xx = idx % 34;
    int t  = idx / 34;
    int rr = t % 34;
    int c  = t / 34;
    int gr = rr - 1, gx = xx - 1;
    float v = 0.f;
    if (gr >= 0 && gr < 32 && gx >= 0 && gx < 32)
      v = x[((size_t)(img * 3 + c) * 32 + gr) * 32 + gx];
    sx[(c * 34 + rr) * 34 + xx] = v;
  }
  __syncthreads();
#pragma unroll 1
  for (int k = 0; k < 4; ++k) {
    int px = k * 256 + tid;
    int yy = px >> 5, xx = px & 31;
    float in27[27];
#pragma unroll
    for (int c = 0; c < 3; ++c)
#pragma unroll
      for (int dy = 0; dy < 3; ++dy)
#pragma unroll
        for (int dx = 0; dx < 3; ++dx)
          in27[c * 9 + dy * 3 + dx] = sx[(c * 34 + yy + dy) * 34 + xx + dx];
#pragma unroll 1
    for (int cbk = 0; cbk < 4; ++cbk) {
      h16 hb[16], lb[16];
#pragma unroll
      for (int j = 0; j < 16; ++j) {
        int co = cbk * 16 + j;
        float acc = 0.f;
#pragma unroll
        for (int t = 0; t < 27; ++t) acc = fmaf(in27[t], wt[t * 64 + co], acc);
        float s = bns[co];
        float yv = fmaxf(fmaf(acc + cb[co], s, bnb[co]), 0.f);
        split2f(yv, hb[j], lb[j]);
      }
      size_t o = 16 + ((size_t)(img * 4 + cbk) * 1024 + px) * 16;
      *(half8*)&oh[o]     = *(half8*)&hb[0];
      *(half8*)&oh[o + 8] = *(half8*)&hb[8];
      *(half8*)&ol[o]     = *(half8*)&lb[0];
      *(half8*)&ol[o + 8] = *(half8*)&lb[8];
    }
  }
}

// ---------------------------------------------------------------------------
// MFMA conv: 3x3 SAME, tap-decomposed implicit GEMM. D = (Ah+Al)*Bh.
// Double-buffered B in LDS, ONE barrier/ck, register-bounce staging.
// A hi/lo direct-from-global with PF-deep prefetch; zero-pad sentinel halo.
// 4 waves/block on one 64-co block; each wave: MT m-tiles x 2 n-tiles.
// ---------------------------------------------------------------------------
template<int H, int W, int CIN, int COUT, int MT, int POOL, int OCC>
__global__ __launch_bounds__(256, OCC) void conv_mfma(
    const h16* __restrict__ Ah, const h16* __restrict__ Al,
    const h16* __restrict__ Wh,
    const float* __restrict__ cb, const float* __restrict__ bns,
    const float* __restrict__ bnb,
    h16* __restrict__ Oh, h16* __restrict__ Ol, float* __restrict__ feats)
{
  constexpr int TPI  = (H * W) / 32;
  constexpr int RPT  = 32 / W;
  constexpr int IPB  = (4 * MT * 32 >= H * W) ? (4 * MT * 32) / (H * W) : 1;
  constexpr int KC   = CIN / 16;
  constexpr int HW   = H * W;
  constexpr int KCO  = COUT / 16;
  constexpr int KCOB = COUT / 64;
  constexpr int LOGW = (W == 32) ? 5 : (W == 16) ? 4 : 3;
  constexpr int PF   = (MT == 1) ? 3 : 2;   // A-prefetch depth (taps in flight)

  __shared__ h16 sBh[2][9 * 2 * 64 * 8];   // 2 x 18.4 KB, [tap][half][co64][c8]
  __shared__ float sRed[(POOL == 2 && MT == 1) ? 256 : 1];

  const int tid  = threadIdx.x;
  const int lane = tid & 63;
  const int wave = tid >> 6;
  const int half = lane >> 5;
  const int col  = lane & 31;
  const int cob  = blockIdx.z;
  const int co0  = cob * 64;

  int aoff[MT], ty[MT], tx[MT], img_t[MT], rw0[MT];
#pragma unroll
  for (int t = 0; t < MT; ++t) {
    int gt   = blockIdx.y * (4 * MT) + wave * MT + t;
    int img  = blockIdx.x * IPB + gt / TPI;
    int row0 = (gt % TPI) * RPT;
    int y = row0 + (col >> LOGW);
    int x = col & (W - 1);
    img_t[t] = img; rw0[t] = row0; ty[t] = y; tx[t] = x;
    aoff[t] = 16 + ((img * KC) * HW + y * W + x) * 16 + half * 8;
  }

  f32x16 acc[MT][2];
#pragma unroll
  for (int t = 0; t < MT; ++t)
#pragma unroll
    for (int n = 0; n < 2; ++n)
#pragma unroll
      for (int i = 0; i < 16; ++i) acc[t][n][i] = 0.f;

  // ---- stage B[0] into buffer 0 ----
#pragma unroll
  for (int i = 0; i < 5; ++i) {
    int id = tid + i * 256;
    if (id < 1152) {
      int src = ((0 * 9 + (id >> 7)) * KCOB + cob) * 1024 + (id & 127) * 8;
      *(half8*)&sBh[0][id * 8] = *(const half8*)(Wh + src);
    }
  }
  __syncthreads();

  int buf = 0;
#pragma unroll 1
  for (int ck = 0; ck < KC; ++ck) {
    // ---- issue next ck's B loads into registers (no LDS op yet) ----
    half8 stg[5];
    const bool have_next = (ck + 1 < KC);
    if (have_next) {
#pragma unroll
      for (int i = 0; i < 5; ++i) {
        int id = tid + i * 256;
        if (id < 1152) {
          int src = (((ck + 1) * 9 + (id >> 7)) * KCOB + cob) * 1024 + (id & 127) * 8;
          stg[i] = *(const half8*)(Wh + src);
        }
      }
    }

    const int ckoA = ck * (HW * 16);
    const h16* bB = sBh[buf];

    // ---- A prefetch pipeline: prologue loads taps 0..PF-1 ----
    half8 pah[PF][MT], pal[PF][MT];
#pragma unroll
    for (int pt = 0; pt < PF; ++pt) {
      const int dy = pt / 3 - 1, dx = pt % 3 - 1;
      const int ashift = (dy * W + dx) * 16;
#pragma unroll
      for (int t = 0; t < MT; ++t) {
        bool v = ((unsigned)(ty[t] + dy) < (unsigned)H) &&
                 ((unsigned)(tx[t] + dx) < (unsigned)W);
        int ai = v ? (aoff[t] + ckoA + ashift) : (half * 8);
        pah[pt][t] = *(const half8*)(Ah + ai);
        pal[pt][t] = *(const half8*)(Al + ai);
      }
    }

#pragma unroll
    for (int tap = 0; tap < 9; ++tap) {
      const int bufr = tap % PF;
      half8 bh[2];
#pragma unroll
      for (int n = 0; n < 2; ++n) {
        int bi = ((tap * 2 + half) * 64 + n * 32 + col) * 8;
        bh[n] = *(const half8*)&bB[bi];
      }
      half8 cah[MT], cal[MT];
#pragma unroll
      for (int t = 0; t < MT; ++t) { cah[t] = pah[bufr][t]; cal[t] = pal[bufr][t]; }
      if (tap + PF < 9) {
        const int pt = tap + PF;
        const int dy = pt / 3 - 1, dx = pt % 3 - 1;
        const int ashift = (dy * W + dx) * 16;
#pragma unroll
        for (int t = 0; t < MT; ++t) {
          bool v = ((unsigned)(ty[t] + dy) < (unsigned)H) &&
                   ((unsigned)(tx[t] + dx) < (unsigned)W);
          int ai = v ? (aoff[t] + ckoA + ashift) : (half * 8);
          pah[bufr][t] = *(const half8*)(Ah + ai);
          pal[bufr][t] = *(const half8*)(Al + ai);
        }
      }
#pragma unroll
      for (int t = 0; t < MT; ++t)
#pragma unroll
        for (int n = 0; n < 2; ++n) {
          acc[t][n] = __builtin_amdgcn_mfma_f32_32x32x16_f16(cah[t], bh[n], acc[t][n], 0, 0, 0);
          acc[t][n] = __builtin_amdgcn_mfma_f32_32x32x16_f16(cal[t], bh[n], acc[t][n], 0, 0, 0);
        }
    }

    // ---- commit staged B into the other buffer, one barrier ----
    if (have_next) {
#pragma unroll
      for (int i = 0; i < 5; ++i) {
        int id = tid + i * 256;
        if (id < 1152)
          *(half8*)&sBh[buf ^ 1][id * 8] = stg[i];
      }
    }
    __syncthreads();
    buf ^= 1;
  }

  // ---- epilogue: y = acc*s + (cb*s+bb), relu, pool, split-store (blocked+16) ----
#pragma unroll
  for (int n = 0; n < 2; ++n) {
    const int co = co0 + n * 32 + col;
    const float es = bns[co];
    const float eb = fmaf(cb[co], es, bnb[co]);
    const int cko = co >> 4, c16 = co & 15;

    if constexpr (POOL == 0) {
#pragma unroll
      for (int t = 0; t < MT; ++t) {
#pragma unroll
        for (int r = 0; r < 16; ++r) {
          float v = fmaxf(fmaf(acc[t][n][r], es, eb), 0.f);
          int m = (r & 3) + 4 * half + 8 * (r >> 2);
          int y = rw0[t] + (m >> LOGW);
          int x = m & (W - 1);
          size_t oi = 16 + ((size_t)(img_t[t] * KCO + cko) * HW + y * W + x) * 16 + c16;
          h16 hh, ll; split2f(v, hh, ll);
          Oh[oi] = hh; Ol[oi] = ll;
        }
      }
    } else if constexpr (POOL == 1 && RPT == 1) {   // conv2: y-pair across tiles
      constexpr int HWq = (H / 2) * (W / 2);
#pragma unroll
      for (int tp = 0; tp < MT / 2; ++tp) {
        const int t0 = 2 * tp, t1 = 2 * tp + 1;
        const int yq = rw0[t0] >> 1;
#pragma unroll
        for (int r = 0; r < 16; r += 2) {
          float v00 = fmaxf(fmaf(acc[t0][n][r],     es, eb), 0.f);
          float v01 = fmaxf(fmaf(acc[t0][n][r + 1], es, eb), 0.f);
          float v10 = fmaxf(fmaf(acc[t1][n][r],     es, eb), 0.f);
          float v11 = fmaxf(fmaf(acc[t1][n][r + 1], es, eb), 0.f);
          float mv = fmaxf(fmaxf(v00, v01), fmaxf(v10, v11));
          int xq = ((r & 3) >> 1) + 2 * half + 4 * (r >> 2);
          size_t oi = 16 + ((size_t)(img_t[t0] * KCO + cko) * HWq + yq * (W / 2) + xq) * 16 + c16;
          h16 hh, ll; split2f(mv, hh, ll);
          Oh[oi] = hh; Ol[oi] = ll;
        }
      }
    } else if constexpr (POOL == 1) {               // conv4 (RPT==2): intra-reg
      constexpr int HWq = (H / 2) * (W / 2);
#pragma unroll
      for (int t = 0; t < MT; ++t) {
        const int yq = rw0[t] >> 1;
#pragma unroll
        for (int r = 0; r < 8; r += 2) {
          float v00 = fmaxf(fmaf(acc[t][n][r],     es, eb), 0.f);
          float v01 = fmaxf(fmaf(acc[t][n][r + 1], es, eb), 0.f);
          float v10 = fmaxf(fmaf(acc[t][n][r + 8], es, eb), 0.f);
          float v11 = fmaxf(fmaf(acc[t][n][r + 9], es, eb), 0.f);
          float mv = fmaxf(fmaxf(v00, v01), fmaxf(v10, v11));
          int xq = ((r & 3) >> 1) + 2 * half + 4 * (r >> 2);
          size_t oi = 16 + ((size_t)(img_t[t] * KCO + cko) * HWq + yq * (W / 2) + xq) * 16 + c16;
          h16 hh, ll; split2f(mv, hh, ll);
          Oh[oi] = hh; Ol[oi] = ll;
        }
      }
    } else if constexpr (POOL == 2 && MT == 1) {    // conv6: 2 waves share an image
      float s = 0.f;
#pragma unroll
      for (int r = 0; r < 16; ++r)
        s += fmaxf(fmaf(acc[0][n][r], es, eb), 0.f);
      s += __shfl_xor(s, 32, 64);                   // full 32-px tile sum
      if (half == 0) sRed[wave * 64 + n * 32 + col] = s;
    } else if constexpr (POOL == 2) {               // MT==2: full image per wave
      float s = 0.f;
#pragma unroll
      for (int t = 0; t < MT; ++t)
#pragma unroll
        for (int r = 0; r < 16; ++r)
          s += fmaxf(fmaf(acc[t][n][r], es, eb), 0.f);
      s += __shfl_xor(s, 32, 64);
      if (half == 0) feats[(size_t)img_t[0] * 256 + co] = s * (1.f / 64.f);
    }
  }

  if constexpr (POOL == 2 && MT == 1) {
    __syncthreads();
    if (tid < 128) {
      int li = tid >> 6, co_l = tid & 63;
      float s = sRed[(li * 2) * 64 + co_l] + sRed[(li * 2 + 1) * 64 + co_l];
      feats[(size_t)(blockIdx.x * 2 + li) * 256 + co0 + co_l] = s * (1.f / 64.f);
    }
  }
}

// ---------------------------------------------------------------------------
// Batched head GEMM (R1, verified).
// ---------------------------------------------------------------------------
template<int O, int K, int LN, int RELU>
__global__ __launch_bounds__(256, 4) void gemm_head(
    const float* __restrict__ A, size_t aStrideE,
    const float* __restrict__ Wm, const float* __restrict__ bias,
    const float* __restrict__ g, const float* __restrict__ bb,
    float* __restrict__ out)
{
  constexpr int KC  = (O >= 256) ? 32 : 64;
  constexpr int WST = O + 4;
  constexpr int TO  = O / 16;
  __shared__ float sA[KC * 68];
  __shared__ float sW[KC * WST];
  __shared__ float mArr[64], rArr[64];

  const int tid  = threadIdx.x;
  const int lane = tid & 63;
  const int wave = tid >> 6;
  const int e    = blockIdx.y;
  const int b0g  = blockIdx.x * 64;
  const int bl   = (lane & 15) * 4;
  const int ol   = wave * (O / 4) + (lane >> 4) * TO;

  const float* Ae = A + (size_t)e * aStrideE;
  const float* We = Wm + (size_t)e * O * K;

  float acc[4][TO];
#pragma unroll
  for (int i = 0; i < 4; ++i)
#pragma unroll
    for (int j = 0; j < TO; ++j) acc[i][j] = 0.f;

  for (int k0 = 0; k0 < K; k0 += KC) {
    for (int idx = tid; idx < 64 * KC; idx += 256) {
      int kk = idx % KC, bb_ = idx / KC;
      sA[kk * 68 + bb_] = Ae[(size_t)(b0g + bb_) * K + k0 + kk];
    }
    for (int idx = tid; idx < O * KC; idx += 256) {
      int kk = idx % KC, oo = idx / KC;
      sW[kk * WST + oo] = We[(size_t)oo * K + k0 + kk];
    }
    __syncthreads();
#pragma unroll 4
    for (int kk = 0; kk < KC; ++kk) {
      float4 av = *(const float4*)&sA[kk * 68 + bl];
      float a4[4] = {av.x, av.y, av.z, av.w};
#pragma unroll
      for (int j4 = 0; j4 < TO; j4 += 4) {
        float4 wv = *(const float4*)&sW[kk * WST + ol + j4];
        float w4[4] = {wv.x, wv.y, wv.z, wv.w};
#pragma unroll
        for (int i = 0; i < 4; ++i)
#pragma unroll
          for (int jj = 0; jj < 4; ++jj)
            acc[i][j4 + jj] = fmaf(a4[i], w4[jj], acc[i][j4 + jj]);
      }
    }
    __syncthreads();
  }

  const float* bi = bias + (size_t)e * O;
#pragma unroll
  for (int i = 0; i < 4; ++i)
#pragma unroll
    for (int j = 0; j < TO; ++j) acc[i][j] += bi[ol + j];

  if constexpr (LN) {
    float* redS = sA;
    float* redQ = sA + 1024;
    const int grp = wave * 4 + (lane >> 4);
#pragma unroll
    for (int i = 0; i < 4; ++i) {
      float s = 0.f, q = 0.f;
#pragma unroll
      for (int j = 0; j < TO; ++j) { s += acc[i][j]; q += acc[i][j] * acc[i][j]; }
      redS[(bl + i) * 16 + grp] = s;
      redQ[(bl + i) * 16 + grp] = q;
    }
    __syncthreads();
    if (tid < 64) {
      float s = 0.f, q = 0.f;
#pragma unroll
      for (int gi = 0; gi < 16; ++gi) { s += redS[tid * 16 + gi]; q += redQ[tid * 16 + gi]; }
      float mean = s * (1.f / O);
      float var  = q * (1.f / O) - mean * mean;
      mArr[tid] = mean;
      rArr[tid] = rsqrtf(var + 1e-5f);
    }
    __syncthreads();
    const float* gp  = g + (size_t)e * O;
    const float* bbp = bb + (size_t)e * O;
#pragma unroll
    for (int i = 0; i < 4; ++i) {
      float mean = mArr[bl + i], rstd = rArr[bl + i];
#pragma unroll
      for (int j = 0; j < TO; ++j)
        acc[i][j] = (acc[i][j] - mean) * rstd * gp[ol + j] + bbp[ol + j];
    }
  }
  if constexpr (RELU) {
#pragma unroll
    for (int i = 0; i < 4; ++i)
#pragma unroll
      for (int j = 0; j < TO; ++j) acc[i][j] = fmaxf(acc[i][j], 0.f);
  }
#pragma unroll
  for (int i = 0; i < 4; ++i) {
    float* op = out + ((size_t)e * 512 + b0g + bl + i) * O + ol;
#pragma unroll
    for (int j4 = 0; j4 < TO; j4 += 4)
      *(float4*)(op + j4) = make_float4(acc[i][j4], acc[i][j4 + 1], acc[i][j4 + 2], acc[i][j4 + 3]);
  }
}

__global__ void cls_softmax_k(const float* __restrict__ embeds,
                              const float* __restrict__ cw,
                              const float* __restrict__ cbias,
                              float* __restrict__ logits_e,
                              float* __restrict__ conf)
{
  int wv   = (blockIdx.x * 256 + threadIdx.x) >> 6;
  int lane = threadIdx.x & 63;
  int b = wv >> 4, e = wv & 15;
  const float* ep = embeds + ((size_t)e * 512 + b) * 128;
  float e0 = ep[lane], e1 = ep[lane + 64];
  float l[10];
#pragma unroll
  for (int o = 0; o < 10; ++o) {
    const float* wp = cw + ((size_t)e * 10 + o) * 128;
    l[o] = e0 * wp[lane] + e1 * wp[lane + 64];
  }
#pragma unroll
  for (int s = 32; s >= 1; s >>= 1)
#pragma unroll
    for (int o = 0; o < 10; ++o) l[o] += __shfl_xor(l[o], s, 64);
#pragma unroll
  for (int o = 0; o < 10; ++o) l[o] += cbias[e * 10 + o];
  float m = l[0];
#pragma unroll
  for (int o = 1; o < 10; ++o) m = fmaxf(m, l[o]);
  float p[10], sum = 0.f;
#pragma unroll
  for (int o = 0; o < 10; ++o) { p[o] = expf(l[o] - m); sum += p[o]; }
  float inv = 1.f / sum, ent = 0.f;
#pragma unroll
  for (int o = 0; o < 10; ++o) { float pp = p[o] * inv; ent -= pp * logf(pp + 1e-12f); }
  if (lane == 0) {
    conf[b * 16 + e] = -ent;
#pragma unroll
    for (int o = 0; o < 10; ++o) logits_e[((size_t)b * 16 + e) * 10 + o] = l[o];
  }
}

__global__ void gate23_k(const float* __restrict__ g1, const float* __restrict__ w2,
                         const float* __restrict__ b2, const float* __restrict__ w3,
                         const float* __restrict__ b3, float* __restrict__ scores)
{
  int wv   = (blockIdx.x * 256 + threadIdx.x) >> 6;
  int lane = threadIdx.x & 63;
  int b = wv >> 4, e = wv & 15;
  float gv = g1[((size_t)e * 512 + b) * 64 + lane];
  const float* w3p = w3 + e * 32;
  float sc = 0.f;
#pragma unroll
  for (int o = 0; o < 32; ++o) {
    float t = gv * w2[((size_t)e * 32 + o) * 64 + lane];
#pragma unroll
    for (int s = 32; s >= 1; s >>= 1) t += __shfl_xor(t, s, 64);
    float g2v = fmaxf(t + b2[e * 32 + o], 0.f);
    sc = fmaf(g2v, w3p[o], sc);
  }
  if (lane == 0) scores[b * 16 + e] = sc + b3[e];
}

__global__ void routing_k(const float* __restrict__ scores, const float* __restrict__ conf,
                          const float* __restrict__ logits_e, float* __restrict__ out)
{
  __shared__ int t2[512];
  __shared__ int chs[512];
  const int tid = threadIdx.x;

  if (tid < 512) {
    int b = tid;
    float v0 = -3.4e38f, v1 = -3.4e38f;
    int i0 = 0, i1 = 0;
#pragma unroll
    for (int e = 0; e < 16; ++e) {
      float s = scores[b * 16 + e];
      float c = conf[b * 16 + e];
      float v = 0.7f * s + 0.3f * c - 0.125f;
      out[5120 + b * 16 + e] = v;
      if (v > v0) { v1 = v0; i1 = i0; v0 = v; i0 = e; }
      else if (v > v1) { v1 = v; i1 = e; }
    }
    t2[b] = i0 | (i1 << 8);
  }
  __syncthreads();

  if (tid < 64) {
    int lane = tid;
    int cnt = 0;
    int pk[8];
#pragma unroll
    for (int k = 0; k < 8; ++k) pk[k] = t2[k * 64 + lane];
#pragma unroll 1
    for (int k = 0; k < 8; ++k) {
      for (int j = 0; j < 64; ++j) {
        int pair = __shfl(pk[k], j, 64);
        int i0 = pair & 0xff, i1 = (pair >> 8) & 0xff;
        int c0 = __shfl(cnt, i0, 64);
        int c1 = __shfl(cnt, i1, 64);
        int ch = (c0 < 64) ? i0 : ((c1 < 64) ? i1 : ((c0 <= c1) ? i0 : i1));
        cnt += (lane == ch) ? 1 : 0;
        if (lane == 0) chs[k * 64 + j] = ch;
      }
    }
  }
  __syncthreads();

  if (tid < 512) {
    int b = tid;
    int ch = chs[b];
#pragma unroll
    for (int e = 0; e < 16; ++e)
      out[13312 + b * 16 + e] = (e == ch) ? 1.0f : 0.0f;
#pragma unroll
    for (int o = 0; o < 10; ++o)
      out[b * 10 + o] = logits_e[((size_t)b * 16 + ch) * 10 + o];
  }
}

// ============================================================================
extern "C" void kernel_launch(void* const* d_in, const int* in_sizes, int n_in,
                              void* d_out, int out_size, void* d_ws, size_t ws_size,
                              hipStream_t stream) {
  (void)in_sizes; (void)n_in; (void)out_size; (void)ws_size;

  const float* x = (const float*)d_in[0];
  const float *cw[6], *cbv[6], *bsv[6], *bbv[6];
  for (int i = 0; i < 6; ++i) {
    cw[i]  = (const float*)d_in[1 + 4 * i];
    cbv[i] = (const float*)d_in[2 + 4 * i];
    bsv[i] = (const float*)d_in[3 + 4 * i];
    bbv[i] = (const float*)d_in[4 + 4 * i];
  }
  const float* gate_w1  = (const float*)d_in[25];
  const float* gate_b1  = (const float*)d_in[26];
  const float* gate_g1  = (const float*)d_in[27];
  const float* gate_bb1 = (const float*)d_in[28];
  const float* gate_w2  = (const float*)d_in[29];
  const float* gate_b2  = (const float*)d_in[30];
  const float* gate_w3  = (const float*)d_in[31];
  const float* gate_b3  = (const float*)d_in[32];
  const float* exp_w1   = (const float*)d_in[33];
  const float* exp_b1   = (const float*)d_in[34];
  const float* exp_g1   = (const float*)d_in[35];
  const float* exp_bb1  = (const float*)d_in[36];
  const float* exp_w2   = (const float*)d_in[37];
  const float* exp_b2   = (const float*)d_in[38];
  const float* exp_g2   = (const float*)d_in[39];
  const float* exp_bb2  = (const float*)d_in[40];
  const float* exp_w3   = (const float*)d_in[41];
  const float* exp_b3   = (const float*)d_in[42];
  const float* cls_w    = (const float*)d_in[43];
  const float* cls_b    = (const float*)d_in[44];

  char* wsb = (char*)d_ws;
  const size_t off_wt1t = 0;
  const size_t off_whi  = 6912;
  const size_t off_Phi  = 4578048;
  const size_t off_Plo  = 71687168;
  const size_t off_Qhi  = 138796288;
  const size_t off_Qlo  = 155573760;
  const size_t off_feats= 172351232;
  const size_t off_h1   = 138796288 + 512;
  const size_t off_h2   = off_h1 + 8388608;
  const size_t off_emb  = off_h2 + 4194304;
  const size_t off_g1   = off_emb + 4194304;
  const size_t off_lg   = off_g1 + 2097152;
  const size_t off_conf = off_lg + 327680;
  const size_t off_sc   = off_conf + 32768;

  float* wt1t = (float*)(wsb + off_wt1t);
  h16* whi = (h16*)(wsb + off_whi);
  h16* Phi = (h16*)(wsb + off_Phi);
  h16* Plo = (h16*)(wsb + off_Plo);
  h16* Qhi = (h16*)(wsb + off_Qhi);
  h16* Qlo = (h16*)(wsb + off_Qlo);
  float* feats = (float*)(wsb + off_feats);
  float* h1 = (float*)(wsb + off_h1);
  float* h2 = (float*)(wsb + off_h2);
  float* emb = (float*)(wsb + off_emb);
  float* g1 = (float*)(wsb + off_g1);
  float* lg = (float*)(wsb + off_lg);
  float* conf = (float*)(wsb + off_conf);
  float* sc = (float*)(wsb + off_sc);

  const size_t wo2 = 0;
  const size_t wo3 = 36864;
  const size_t wo4 = 110592;
  const size_t wo5 = 258048;
  const size_t wo6 = 552960;

  // ---- fused prep (pads + wt1 transpose + all weight splits) ----
  prep_all_k<<<4471, 256, 0, stream>>>(cw[0], cw[1], cw[2], cw[3], cw[4], cw[5],
                                       wt1t, whi, Phi, Plo, Qhi, Qlo);

  // ---- trunk ----
  conv1_k<<<512, 256, 0, stream>>>(x, wt1t, cbv[0], bsv[0], bbv[0], Phi, Plo);
  // <H, W, CIN, COUT, MT, POOL, OCC>
  conv_mfma<32, 32, 64, 64, 2, 1, 3><<<dim3(512, 4, 1), 256, 0, stream>>>(
      Phi, Plo, whi + wo2, cbv[1], bsv[1], bbv[1], Qhi, Qlo, nullptr);
  conv_mfma<16, 16, 64, 128, 2, 0, 3><<<dim3(512, 1, 2), 256, 0, stream>>>(
      Qhi, Qlo, whi + wo3, cbv[2], bsv[2], bbv[2], Phi, Plo, nullptr);
  conv_mfma<16, 16, 128, 128, 2, 1, 3><<<dim3(512, 1, 2), 256, 0, stream>>>(
      Phi, Plo, whi + wo4, cbv[3], bsv[3], bbv[3], Qhi, Qlo, nullptr);
  conv_mfma<8, 8, 128, 256, 1, 0, 4><<<dim3(256, 1, 4), 256, 0, stream>>>(
      Qhi, Qlo, whi + wo5, cbv[4], bsv[4], bbv[4], Phi, Plo, nullptr);
  conv_mfma<8, 8, 256, 256, 1, 2, 4><<<dim3(256, 1, 4), 256, 0, stream>>>(
      Phi, Plo, whi + wo6, cbv[5], bsv[5], bbv[5], nullptr, nullptr, feats);

  // ---- experts ----
  gemm_head<256, 256, 1, 1><<<dim3(8, 16), 256, 0, stream>>>(
      feats, (size_t)0, exp_w1, exp_b1, exp_g1, exp_bb1, h1);
  gemm_head<128, 256, 1, 1><<<dim3(8, 16), 256, 0, stream>>>(
      h1, (size_t)512 * 256, exp_w2, exp_b2, exp_g2, exp_bb2, h2);
  gemm_head<128, 128, 0, 0><<<dim3(8, 16), 256, 0, stream>>>(
      h2, (size_t)512 * 128, exp_w3, exp_b3, nullptr, nullptr, emb);
  cls_softmax_k<<<2048, 256, 0, stream>>>(emb, cls_w, cls_b, lg, conf);

  // ---- gates ----
  gemm_head<64, 256, 1, 1><<<dim3(8, 16), 256, 0, stream>>>(
      feats, (size_t)0, gate_w1, gate_b1, gate_g1, gate_bb1, g1);
  gate23_k<<<2048, 256, 0, stream>>>(g1, gate_w2, gate_b2, gate_w3, gate_b3, sc);

  // ---- routing + outputs ----
  routing_k<<<1, 512, 0, stream>>>(sc, conf, lg, (float*)d_out);
}

// Round 17
// 728.854 us; speedup vs baseline: 1.2248x; 1.0797x over previous
//
#include <hip/hip_runtime.h>

// ============================================================================
// ImprovedMoE R17 = R16/R14 + gemm_head batch-tile 64->32 (grid 128->256
// blocks: R16 ran heads on half the GPU). Per-output arithmetic bitwise
// identical (same K order, same LN group order) -> absmax unchanged.
// Trunk: D=(Ah+Al)*Bh, single-barrier dbuf B in LDS, PF A-prefetch (R14).
// ============================================================================

typedef _Float16 h16;
typedef _Float16 half8 __attribute__((ext_vector_type(8)));
typedef float f32x16 __attribute__((ext_vector_type(16)));

__device__ __forceinline__ void split2f(float x, h16& hh, h16& ll) {
  h16 a = (h16)x;
  hh = a;
  ll = (h16)(x - (float)a);
}

// ---- fused prep: zero pads + conv1 wt transpose + conv2..6 weight split ----
__global__ void prep_all_k(const float* __restrict__ cw1, const float* __restrict__ cw2,
                           const float* __restrict__ cw3, const float* __restrict__ cw4,
                           const float* __restrict__ cw5, const float* __restrict__ cw6,
                           float* __restrict__ wt1t, h16* __restrict__ wh,
                           h16* p0, h16* p1, h16* p2, h16* p3) {
  int idx = blockIdx.x * 256 + threadIdx.x;
  if (idx < 64) {
    h16* p = (idx < 16) ? p0 : (idx < 32) ? p1 : (idx < 48) ? p2 : p3;
    p[idx & 15] = (h16)0.f;
    return;
  }
  idx -= 64;
  if (idx < 1728) {
    int co = idx % 64, r = idx / 64;
    wt1t[idx] = cw1[(size_t)co * 27 + r];
    return;
  }
  idx -= 1728;
  const float* w; int CIN, COUT; size_t off;
  if (idx < 36864)        { w = cw2; CIN = 64;  COUT = 64;  off = 0; }
  else if (idx < 110592)  { w = cw3; CIN = 64;  COUT = 128; off = 36864;  idx -= 36864; }
  else if (idx < 258048)  { w = cw4; CIN = 128; COUT = 128; off = 110592; idx -= 110592; }
  else if (idx < 552960)  { w = cw5; CIN = 128; COUT = 256; off = 258048; idx -= 258048; }
  else if (idx < 1142784) { w = cw6; CIN = 256; COUT = 256; off = 552960; idx -= 552960; }
  else return;
  int KCOB = COUT >> 6;
  int lidx = idx;
  int c8   = idx & 7;
  int t    = idx >> 3;
  int co64 = t & 63;  t >>= 6;
  int half = t & 1;   t >>= 1;
  int cob  = t % KCOB; t /= KCOB;
  int tap  = t % 9;
  int ck   = t / 9;
  int ci = ck * 16 + half * 8 + c8;
  int co = cob * 64 + co64;
  float v = w[((size_t)co * CIN + ci) * 9 + tap];
  wh[off + lidx] = (h16)v;
}

// ---- conv1: 3->64, 32x32, fp32 vector; outputs blocked hi/lo planes (+16) ----
__global__ __launch_bounds__(256) void conv1_k(
    const float* __restrict__ x, const float* __restrict__ wt,
    const float* __restrict__ cb, const float* __restrict__ bns,
    const float* __restrict__ bnb, h16* __restrict__ oh, h16* __restrict__ ol)
{
  __shared__ float sx[3 * 34 * 34];
  const int tid = threadIdx.x;
  const int img = blockIdx.x;
  for (int idx = tid; idx < 3 * 34 * 34; idx += 256) {
    int xx = idx % 34;
    int t  = idx / 34;
    int rr = t % 34;
    int c  = t / 34;
    int gr = rr - 1, gx = xx - 1;
    float v = 0.f;
    if (gr >= 0 && gr < 32 && gx >= 0 && gx < 32)
      v = x[((size_t)(img * 3 + c) * 32 + gr) * 32 + gx];
    sx[(c * 34 + rr) * 34 + xx] = v;
  }
  __syncthreads();
#pragma unroll 1
  for (int k = 0; k < 4; ++k) {
    int px = k * 256 + tid;
    int yy = px >> 5, xx = px & 31;
    float in27[27];
#pragma unroll
    for (int c = 0; c < 3; ++c)
#pragma unroll
      for (int dy = 0; dy < 3; ++dy)
#pragma unroll
        for (int dx = 0; dx < 3; ++dx)
          in27[c * 9 + dy * 3 + dx] = sx[(c * 34 + yy + dy) * 34 + xx + dx];
#pragma unroll 1
    for (int cbk = 0; cbk < 4; ++cbk) {
      h16 hb[16], lb[16];
#pragma unroll
      for (int j = 0; j < 16; ++j) {
        int co = cbk * 16 + j;
        float acc = 0.f;
#pragma unroll
        for (int t = 0; t < 27; ++t) acc = fmaf(in27[t], wt[t * 64 + co], acc);
        float s = bns[co];
        float yv = fmaxf(fmaf(acc + cb[co], s, bnb[co]), 0.f);
        split2f(yv, hb[j], lb[j]);
      }
      size_t o = 16 + ((size_t)(img * 4 + cbk) * 1024 + px) * 16;
      *(half8*)&oh[o]     = *(half8*)&hb[0];
      *(half8*)&oh[o + 8] = *(half8*)&hb[8];
      *(half8*)&ol[o]     = *(half8*)&lb[0];
      *(half8*)&ol[o + 8] = *(half8*)&lb[8];
    }
  }
}

// ---------------------------------------------------------------------------
// MFMA conv: 3x3 SAME, tap-decomposed implicit GEMM. D = (Ah+Al)*Bh.
// Double-buffered B in LDS, ONE barrier/ck, register-bounce staging.
// A hi/lo direct-from-global with PF-deep prefetch; zero-pad sentinel halo.
// ---------------------------------------------------------------------------
template<int H, int W, int CIN, int COUT, int MT, int POOL, int OCC>
__global__ __launch_bounds__(256, OCC) void conv_mfma(
    const h16* __restrict__ Ah, const h16* __restrict__ Al,
    const h16* __restrict__ Wh,
    const float* __restrict__ cb, const float* __restrict__ bns,
    const float* __restrict__ bnb,
    h16* __restrict__ Oh, h16* __restrict__ Ol, float* __restrict__ feats)
{
  constexpr int TPI  = (H * W) / 32;
  constexpr int RPT  = 32 / W;
  constexpr int IPB  = (4 * MT * 32 >= H * W) ? (4 * MT * 32) / (H * W) : 1;
  constexpr int KC   = CIN / 16;
  constexpr int HW   = H * W;
  constexpr int KCO  = COUT / 16;
  constexpr int KCOB = COUT / 64;
  constexpr int LOGW = (W == 32) ? 5 : (W == 16) ? 4 : 3;
  constexpr int PF   = (MT == 1) ? 3 : 2;

  __shared__ h16 sBh[2][9 * 2 * 64 * 8];
  __shared__ float sRed[(POOL == 2 && MT == 1) ? 256 : 1];

  const int tid  = threadIdx.x;
  const int lane = tid & 63;
  const int wave = tid >> 6;
  const int half = lane >> 5;
  const int col  = lane & 31;
  const int cob  = blockIdx.z;
  const int co0  = cob * 64;

  int aoff[MT], ty[MT], tx[MT], img_t[MT], rw0[MT];
#pragma unroll
  for (int t = 0; t < MT; ++t) {
    int gt   = blockIdx.y * (4 * MT) + wave * MT + t;
    int img  = blockIdx.x * IPB + gt / TPI;
    int row0 = (gt % TPI) * RPT;
    int y = row0 + (col >> LOGW);
    int x = col & (W - 1);
    img_t[t] = img; rw0[t] = row0; ty[t] = y; tx[t] = x;
    aoff[t] = 16 + ((img * KC) * HW + y * W + x) * 16 + half * 8;
  }

  f32x16 acc[MT][2];
#pragma unroll
  for (int t = 0; t < MT; ++t)
#pragma unroll
    for (int n = 0; n < 2; ++n)
#pragma unroll
      for (int i = 0; i < 16; ++i) acc[t][n][i] = 0.f;

#pragma unroll
  for (int i = 0; i < 5; ++i) {
    int id = tid + i * 256;
    if (id < 1152) {
      int src = ((0 * 9 + (id >> 7)) * KCOB + cob) * 1024 + (id & 127) * 8;
      *(half8*)&sBh[0][id * 8] = *(const half8*)(Wh + src);
    }
  }
  __syncthreads();

  int buf = 0;
#pragma unroll 1
  for (int ck = 0; ck < KC; ++ck) {
    half8 stg[5];
    const bool have_next = (ck + 1 < KC);
    if (have_next) {
#pragma unroll
      for (int i = 0; i < 5; ++i) {
        int id = tid + i * 256;
        if (id < 1152) {
          int src = (((ck + 1) * 9 + (id >> 7)) * KCOB + cob) * 1024 + (id & 127) * 8;
          stg[i] = *(const half8*)(Wh + src);
        }
      }
    }

    const int ckoA = ck * (HW * 16);
    const h16* bB = sBh[buf];

    half8 pah[PF][MT], pal[PF][MT];
#pragma unroll
    for (int pt = 0; pt < PF; ++pt) {
      const int dy = pt / 3 - 1, dx = pt % 3 - 1;
      const int ashift = (dy * W + dx) * 16;
#pragma unroll
      for (int t = 0; t < MT; ++t) {
        bool v = ((unsigned)(ty[t] + dy) < (unsigned)H) &&
                 ((unsigned)(tx[t] + dx) < (unsigned)W);
        int ai = v ? (aoff[t] + ckoA + ashift) : (half * 8);
        pah[pt][t] = *(const half8*)(Ah + ai);
        pal[pt][t] = *(const half8*)(Al + ai);
      }
    }

#pragma unroll
    for (int tap = 0; tap < 9; ++tap) {
      const int bufr = tap % PF;
      half8 bh[2];
#pragma unroll
      for (int n = 0; n < 2; ++n) {
        int bi = ((tap * 2 + half) * 64 + n * 32 + col) * 8;
        bh[n] = *(const half8*)&bB[bi];
      }
      half8 cah[MT], cal[MT];
#pragma unroll
      for (int t = 0; t < MT; ++t) { cah[t] = pah[bufr][t]; cal[t] = pal[bufr][t]; }
      if (tap + PF < 9) {
        const int pt = tap + PF;
        const int dy = pt / 3 - 1, dx = pt % 3 - 1;
        const int ashift = (dy * W + dx) * 16;
#pragma unroll
        for (int t = 0; t < MT; ++t) {
          bool v = ((unsigned)(ty[t] + dy) < (unsigned)H) &&
                   ((unsigned)(tx[t] + dx) < (unsigned)W);
          int ai = v ? (aoff[t] + ckoA + ashift) : (half * 8);
          pah[bufr][t] = *(const half8*)(Ah + ai);
          pal[bufr][t] = *(const half8*)(Al + ai);
        }
      }
#pragma unroll
      for (int t = 0; t < MT; ++t)
#pragma unroll
        for (int n = 0; n < 2; ++n) {
          acc[t][n] = __builtin_amdgcn_mfma_f32_32x32x16_f16(cah[t], bh[n], acc[t][n], 0, 0, 0);
          acc[t][n] = __builtin_amdgcn_mfma_f32_32x32x16_f16(cal[t], bh[n], acc[t][n], 0, 0, 0);
        }
    }

    if (have_next) {
#pragma unroll
      for (int i = 0; i < 5; ++i) {
        int id = tid + i * 256;
        if (id < 1152)
          *(half8*)&sBh[buf ^ 1][id * 8] = stg[i];
      }
    }
    __syncthreads();
    buf ^= 1;
  }

#pragma unroll
  for (int n = 0; n < 2; ++n) {
    const int co = co0 + n * 32 + col;
    const float es = bns[co];
    const float eb = fmaf(cb[co], es, bnb[co]);
    const int cko = co >> 4, c16 = co & 15;

    if constexpr (POOL == 0) {
#pragma unroll
      for (int t = 0; t < MT; ++t) {
#pragma unroll
        for (int r = 0; r < 16; ++r) {
          float v = fmaxf(fmaf(acc[t][n][r], es, eb), 0.f);
          int m = (r & 3) + 4 * half + 8 * (r >> 2);
          int y = rw0[t] + (m >> LOGW);
          int x = m & (W - 1);
          size_t oi = 16 + ((size_t)(img_t[t] * KCO + cko) * HW + y * W + x) * 16 + c16;
          h16 hh, ll; split2f(v, hh, ll);
          Oh[oi] = hh; Ol[oi] = ll;
        }
      }
    } else if constexpr (POOL == 1 && RPT == 1) {
      constexpr int HWq = (H / 2) * (W / 2);
#pragma unroll
      for (int tp = 0; tp < MT / 2; ++tp) {
        const int t0 = 2 * tp, t1 = 2 * tp + 1;
        const int yq = rw0[t0] >> 1;
#pragma unroll
        for (int r = 0; r < 16; r += 2) {
          float v00 = fmaxf(fmaf(acc[t0][n][r],     es, eb), 0.f);
          float v01 = fmaxf(fmaf(acc[t0][n][r + 1], es, eb), 0.f);
          float v10 = fmaxf(fmaf(acc[t1][n][r],     es, eb), 0.f);
          float v11 = fmaxf(fmaf(acc[t1][n][r + 1], es, eb), 0.f);
          float mv = fmaxf(fmaxf(v00, v01), fmaxf(v10, v11));
          int xq = ((r & 3) >> 1) + 2 * half + 4 * (r >> 2);
          size_t oi = 16 + ((size_t)(img_t[t0] * KCO + cko) * HWq + yq * (W / 2) + xq) * 16 + c16;
          h16 hh, ll; split2f(mv, hh, ll);
          Oh[oi] = hh; Ol[oi] = ll;
        }
      }
    } else if constexpr (POOL == 1) {
      constexpr int HWq = (H / 2) * (W / 2);
#pragma unroll
      for (int t = 0; t < MT; ++t) {
        const int yq = rw0[t] >> 1;
#pragma unroll
        for (int r = 0; r < 8; r += 2) {
          float v00 = fmaxf(fmaf(acc[t][n][r],     es, eb), 0.f);
          float v01 = fmaxf(fmaf(acc[t][n][r + 1], es, eb), 0.f);
          float v10 = fmaxf(fmaf(acc[t][n][r + 8], es, eb), 0.f);
          float v11 = fmaxf(fmaf(acc[t][n][r + 9], es, eb), 0.f);
          float mv = fmaxf(fmaxf(v00, v01), fmaxf(v10, v11));
          int xq = ((r & 3) >> 1) + 2 * half + 4 * (r >> 2);
          size_t oi = 16 + ((size_t)(img_t[t] * KCO + cko) * HWq + yq * (W / 2) + xq) * 16 + c16;
          h16 hh, ll; split2f(mv, hh, ll);
          Oh[oi] = hh; Ol[oi] = ll;
        }
      }
    } else if constexpr (POOL == 2 && MT == 1) {
      float s = 0.f;
#pragma unroll
      for (int r = 0; r < 16; ++r)
        s += fmaxf(fmaf(acc[0][n][r], es, eb), 0.f);
      s += __shfl_xor(s, 32, 64);
      if (half == 0) sRed[wave * 64 + n * 32 + col] = s;
    } else if constexpr (POOL == 2) {
      float s = 0.f;
#pragma unroll
      for (int t = 0; t < MT; ++t)
#pragma unroll
        for (int r = 0; r < 16; ++r)
          s += fmaxf(fmaf(acc[t][n][r], es, eb), 0.f);
      s += __shfl_xor(s, 32, 64);
      if (half == 0) feats[(size_t)img_t[0] * 256 + co] = s * (1.f / 64.f);
    }
  }

  if constexpr (POOL == 2 && MT == 1) {
    __syncthreads();
    if (tid < 128) {
      int li = tid >> 6, co_l = tid & 63;
      float s = sRed[(li * 2) * 64 + co_l] + sRed[(li * 2 + 1) * 64 + co_l];
      feats[(size_t)(blockIdx.x * 2 + li) * 256 + co0 + co_l] = s * (1.f / 64.f);
    }
  }
}

// ---------------------------------------------------------------------------
// Batched head GEMM: 32 batch rows/block (grid.x=16 -> 256 blocks).
// Per-output arithmetic identical to the 64-row version (same K order,
// same LN 16-group reduction order per row).
// ---------------------------------------------------------------------------
template<int O, int K, int LN, int RELU>
__global__ __launch_bounds__(256, 4) void gemm_head(
    const float* __restrict__ A, size_t aStrideE,
    const float* __restrict__ Wm, const float* __restrict__ bias,
    const float* __restrict__ g, const float* __restrict__ bb,
    float* __restrict__ out)
{
  constexpr int KC  = (O >= 256) ? 32 : 64;
  constexpr int WST = O + 4;
  constexpr int TO  = O / 16;
  __shared__ float sA[KC * 36];
  __shared__ float sW[KC * WST];
  __shared__ float mArr[32], rArr[32];

  const int tid  = threadIdx.x;
  const int lane = tid & 63;
  const int wave = tid >> 6;
  const int e    = blockIdx.y;
  const int b0g  = blockIdx.x * 32;
  const int bl   = (lane & 15) * 2;
  const int ol   = wave * (O / 4) + (lane >> 4) * TO;

  const float* Ae = A + (size_t)e * aStrideE;
  const float* We = Wm + (size_t)e * O * K;

  float acc[2][TO];
#pragma unroll
  for (int i = 0; i < 2; ++i)
#pragma unroll
    for (int j = 0; j < TO; ++j) acc[i][j] = 0.f;

  for (int k0 = 0; k0 < K; k0 += KC) {
    for (int idx = tid; idx < 32 * KC; idx += 256) {
      int kk = idx % KC, bb_ = idx / KC;
      sA[kk * 36 + bb_] = Ae[(size_t)(b0g + bb_) * K + k0 + kk];
    }
    for (int idx = tid; idx < O * KC; idx += 256) {
      int kk = idx % KC, oo = idx / KC;
      sW[kk * WST + oo] = We[(size_t)oo * K + k0 + kk];
    }
    __syncthreads();
#pragma unroll 4
    for (int kk = 0; kk < KC; ++kk) {
      float2 av = *(const float2*)&sA[kk * 36 + bl];
      float a2[2] = {av.x, av.y};
#pragma unroll
      for (int j4 = 0; j4 < TO; j4 += 4) {
        float4 wv = *(const float4*)&sW[kk * WST + ol + j4];
        float w4[4] = {wv.x, wv.y, wv.z, wv.w};
#pragma unroll
        for (int i = 0; i < 2; ++i)
#pragma unroll
          for (int jj = 0; jj < 4; ++jj)
            acc[i][j4 + jj] = fmaf(a2[i], w4[jj], acc[i][j4 + jj]);
      }
    }
    __syncthreads();
  }

  const float* bi = bias + (size_t)e * O;
#pragma unroll
  for (int i = 0; i < 2; ++i)
#pragma unroll
    for (int j = 0; j < TO; ++j) acc[i][j] += bi[ol + j];

  if constexpr (LN) {
    float* redS = sA;             // >= 512 floats
    float* redQ = sA + 512;
    const int grp = wave * 4 + (lane >> 4);
#pragma unroll
    for (int i = 0; i < 2; ++i) {
      float s = 0.f, q = 0.f;
#pragma unroll
      for (int j = 0; j < TO; ++j) { s += acc[i][j]; q += acc[i][j] * acc[i][j]; }
      redS[(bl + i) * 16 + grp] = s;
      redQ[(bl + i) * 16 + grp] = q;
    }
    __syncthreads();
    if (tid < 32) {
      float s = 0.f, q = 0.f;
#pragma unroll
      for (int gi = 0; gi < 16; ++gi) { s += redS[tid * 16 + gi]; q += redQ[tid * 16 + gi]; }
      float mean = s * (1.f / O);
      float var  = q * (1.f / O) - mean * mean;
      mArr[tid] = mean;
      rArr[tid] = rsqrtf(var + 1e-5f);
    }
    __syncthreads();
    const float* gp  = g + (size_t)e * O;
    const float* bbp = bb + (size_t)e * O;
#pragma unroll
    for (int i = 0; i < 2; ++i) {
      float mean = mArr[bl + i], rstd = rArr[bl + i];
#pragma unroll
      for (int j = 0; j < TO; ++j)
        acc[i][j] = (acc[i][j] - mean) * rstd * gp[ol + j] + bbp[ol + j];
    }
  }
  if constexpr (RELU) {
#pragma unroll
    for (int i = 0; i < 2; ++i)
#pragma unroll
      for (int j = 0; j < TO; ++j) acc[i][j] = fmaxf(acc[i][j], 0.f);
  }
#pragma unroll
  for (int i = 0; i < 2; ++i) {
    float* op = out + ((size_t)e * 512 + b0g + bl + i) * O + ol;
#pragma unroll
    for (int j4 = 0; j4 < TO; j4 += 4)
      *(float4*)(op + j4) = make_float4(acc[i][j4], acc[i][j4 + 1], acc[i][j4 + 2], acc[i][j4 + 3]);
  }
}

__global__ void cls_softmax_k(const float* __restrict__ embeds,
                              const float* __restrict__ cw,
                              const float* __restrict__ cbias,
                              float* __restrict__ logits_e,
                              float* __restrict__ conf)
{
  int wv   = (blockIdx.x * 256 + threadIdx.x) >> 6;
  int lane = threadIdx.x & 63;
  int b = wv >> 4, e = wv & 15;
  const float* ep = embeds + ((size_t)e * 512 + b) * 128;
  float e0 = ep[lane], e1 = ep[lane + 64];
  float l[10];
#pragma unroll
  for (int o = 0; o < 10; ++o) {
    const float* wp = cw + ((size_t)e * 10 + o) * 128;
    l[o] = e0 * wp[lane] + e1 * wp[lane + 64];
  }
#pragma unroll
  for (int s = 32; s >= 1; s >>= 1)
#pragma unroll
    for (int o = 0; o < 10; ++o) l[o] += __shfl_xor(l[o], s, 64);
#pragma unroll
  for (int o = 0; o < 10; ++o) l[o] += cbias[e * 10 + o];
  float m = l[0];
#pragma unroll
  for (int o = 1; o < 10; ++o) m = fmaxf(m, l[o]);
  float p[10], sum = 0.f;
#pragma unroll
  for (int o = 0; o < 10; ++o) { p[o] = expf(l[o] - m); sum += p[o]; }
  float inv = 1.f / sum, ent = 0.f;
#pragma unroll
  for (int o = 0; o < 10; ++o) { float pp = p[o] * inv; ent -= pp * logf(pp + 1e-12f); }
  if (lane == 0) {
    conf[b * 16 + e] = -ent;
#pragma unroll
    for (int o = 0; o < 10; ++o) logits_e[((size_t)b * 16 + e) * 10 + o] = l[o];
  }
}

__global__ void gate23_k(const float* __restrict__ g1, const float* __restrict__ w2,
                         const float* __restrict__ b2, const float* __restrict__ w3,
                         const float* __restrict__ b3, float* __restrict__ scores)
{
  int wv   = (blockIdx.x * 256 + threadIdx.x) >> 6;
  int lane = threadIdx.x & 63;
  int b = wv >> 4, e = wv & 15;
  float gv = g1[((size_t)e * 512 + b) * 64 + lane];
  const float* w3p = w3 + e * 32;
  float sc = 0.f;
#pragma unroll
  for (int o = 0; o < 32; ++o) {
    float t = gv * w2[((size_t)e * 32 + o) * 64 + lane];
#pragma unroll
    for (int s = 32; s >= 1; s >>= 1) t += __shfl_xor(t, s, 64);
    float g2v = fmaxf(t + b2[e * 32 + o], 0.f);
    sc = fmaf(g2v, w3p[o], sc);
  }
  if (lane == 0) scores[b * 16 + e] = sc + b3[e];
}

__global__ void routing_k(const float* __restrict__ scores, const float* __restrict__ conf,
                          const float* __restrict__ logits_e, float* __restrict__ out)
{
  __shared__ int t2[512];
  __shared__ int chs[512];
  const int tid = threadIdx.x;

  if (tid < 512) {
    int b = tid;
    float v0 = -3.4e38f, v1 = -3.4e38f;
    int i0 = 0, i1 = 0;
#pragma unroll
    for (int e = 0; e < 16; ++e) {
      float s = scores[b * 16 + e];
      float c = conf[b * 16 + e];
      float v = 0.7f * s + 0.3f * c - 0.125f;
      out[5120 + b * 16 + e] = v;
      if (v > v0) { v1 = v0; i1 = i0; v0 = v; i0 = e; }
      else if (v > v1) { v1 = v; i1 = e; }
    }
    t2[b] = i0 | (i1 << 8);
  }
  __syncthreads();

  if (tid < 64) {
    int lane = tid;
    int cnt = 0;
    int pk[8];
#pragma unroll
    for (int k = 0; k < 8; ++k) pk[k] = t2[k * 64 + lane];
#pragma unroll 1
    for (int k = 0; k < 8; ++k) {
      for (int j = 0; j < 64; ++j) {
        int pair = __shfl(pk[k], j, 64);
        int i0 = pair & 0xff, i1 = (pair >> 8) & 0xff;
        int c0 = __shfl(cnt, i0, 64);
        int c1 = __shfl(cnt, i1, 64);
        int ch = (c0 < 64) ? i0 : ((c1 < 64) ? i1 : ((c0 <= c1) ? i0 : i1));
        cnt += (lane == ch) ? 1 : 0;
        if (lane == 0) chs[k * 64 + j] = ch;
      }
    }
  }
  __syncthreads();

  if (tid < 512) {
    int b = tid;
    int ch = chs[b];
#pragma unroll
    for (int e = 0; e < 16; ++e)
      out[13312 + b * 16 + e] = (e == ch) ? 1.0f : 0.0f;
#pragma unroll
    for (int o = 0; o < 10; ++o)
      out[b * 10 + o] = logits_e[((size_t)b * 16 + ch) * 10 + o];
  }
}

// ============================================================================
extern "C" void kernel_launch(void* const* d_in, const int* in_sizes, int n_in,
                              void* d_out, int out_size, void* d_ws, size_t ws_size,
                              hipStream_t stream) {
  (void)in_sizes; (void)n_in; (void)out_size; (void)ws_size;

  const float* x = (const float*)d_in[0];
  const float *cw[6], *cbv[6], *bsv[6], *bbv[6];
  for (int i = 0; i < 6; ++i) {
    cw[i]  = (const float*)d_in[1 + 4 * i];
    cbv[i] = (const float*)d_in[2 + 4 * i];
    bsv[i] = (const float*)d_in[3 + 4 * i];
    bbv[i] = (const float*)d_in[4 + 4 * i];
  }
  const float* gate_w1  = (const float*)d_in[25];
  const float* gate_b1  = (const float*)d_in[26];
  const float* gate_g1  = (const float*)d_in[27];
  const float* gate_bb1 = (const float*)d_in[28];
  const float* gate_w2  = (const float*)d_in[29];
  const float* gate_b2  = (const float*)d_in[30];
  const float* gate_w3  = (const float*)d_in[31];
  const float* gate_b3  = (const float*)d_in[32];
  const float* exp_w1   = (const float*)d_in[33];
  const float* exp_b1   = (const float*)d_in[34];
  const float* exp_g1   = (const float*)d_in[35];
  const float* exp_bb1  = (const float*)d_in[36];
  const float* exp_w2   = (const float*)d_in[37];
  const float* exp_b2   = (const float*)d_in[38];
  const float* exp_g2   = (const float*)d_in[39];
  const float* exp_bb2  = (const float*)d_in[40];
  const float* exp_w3   = (const float*)d_in[41];
  const float* exp_b3   = (const float*)d_in[42];
  const float* cls_w    = (const float*)d_in[43];
  const float* cls_b    = (const float*)d_in[44];

  char* wsb = (char*)d_ws;
  const size_t off_wt1t = 0;
  const size_t off_whi  = 6912;
  const size_t off_Phi  = 4578048;
  const size_t off_Plo  = 71687168;
  const size_t off_Qhi  = 138796288;
  const size_t off_Qlo  = 155573760;
  const size_t off_feats= 172351232;
  const size_t off_h1   = 138796288 + 512;
  const size_t off_h2   = off_h1 + 8388608;
  const size_t off_emb  = off_h2 + 4194304;
  const size_t off_g1   = off_emb + 4194304;
  const size_t off_lg   = off_g1 + 2097152;
  const size_t off_conf = off_lg + 327680;
  const size_t off_sc   = off_conf + 32768;

  float* wt1t = (float*)(wsb + off_wt1t);
  h16* whi = (h16*)(wsb + off_whi);
  h16* Phi = (h16*)(wsb + off_Phi);
  h16* Plo = (h16*)(wsb + off_Plo);
  h16* Qhi = (h16*)(wsb + off_Qhi);
  h16* Qlo = (h16*)(wsb + off_Qlo);
  float* feats = (float*)(wsb + off_feats);
  float* h1 = (float*)(wsb + off_h1);
  float* h2 = (float*)(wsb + off_h2);
  float* emb = (float*)(wsb + off_emb);
  float* g1 = (float*)(wsb + off_g1);
  float* lg = (float*)(wsb + off_lg);
  float* conf = (float*)(wsb + off_conf);
  float* sc = (float*)(wsb + off_sc);

  const size_t wo2 = 0;
  const size_t wo3 = 36864;
  const size_t wo4 = 110592;
  const size_t wo5 = 258048;
  const size_t wo6 = 552960;

  // ---- fused prep (pads + wt1 transpose + all weight splits) ----
  prep_all_k<<<4471, 256, 0, stream>>>(cw[0], cw[1], cw[2], cw[3], cw[4], cw[5],
                                       wt1t, whi, Phi, Plo, Qhi, Qlo);

  // ---- trunk ----
  conv1_k<<<512, 256, 0, stream>>>(x, wt1t, cbv[0], bsv[0], bbv[0], Phi, Plo);
  // <H, W, CIN, COUT, MT, POOL, OCC>
  conv_mfma<32, 32, 64, 64, 2, 1, 3><<<dim3(512, 4, 1), 256, 0, stream>>>(
      Phi, Plo, whi + wo2, cbv[1], bsv[1], bbv[1], Qhi, Qlo, nullptr);
  conv_mfma<16, 16, 64, 128, 2, 0, 3><<<dim3(512, 1, 2), 256, 0, stream>>>(
      Qhi, Qlo, whi + wo3, cbv[2], bsv[2], bbv[2], Phi, Plo, nullptr);
  conv_mfma<16, 16, 128, 128, 2, 1, 3><<<dim3(512, 1, 2), 256, 0, stream>>>(
      Phi, Plo, whi + wo4, cbv[3], bsv[3], bbv[3], Qhi, Qlo, nullptr);
  conv_mfma<8, 8, 128, 256, 1, 0, 4><<<dim3(256, 1, 4), 256, 0, stream>>>(
      Qhi, Qlo, whi + wo5, cbv[4], bsv[4], bbv[4], Phi, Plo, nullptr);
  conv_mfma<8, 8, 256, 256, 1, 2, 4><<<dim3(256, 1, 4), 256, 0, stream>>>(
      Phi, Plo, whi + wo6, cbv[5], bsv[5], bbv[5], nullptr, nullptr, feats);

  // ---- experts (grid.x=16 -> 256 blocks, full GPU) ----
  gemm_head<256, 256, 1, 1><<<dim3(16, 16), 256, 0, stream>>>(
      feats, (size_t)0, exp_w1, exp_b1, exp_g1, exp_bb1, h1);
  gemm_head<128, 256, 1, 1><<<dim3(16, 16), 256, 0, stream>>>(
      h1, (size_t)512 * 256, exp_w2, exp_b2, exp_g2, exp_bb2, h2);
  gemm_head<128, 128, 0, 0><<<dim3(16, 16), 256, 0, stream>>>(
      h2, (size_t)512 * 128, exp_w3, exp_b3, nullptr, nullptr, emb);
  cls_softmax_k<<<2048, 256, 0, stream>>>(emb, cls_w, cls_b, lg, conf);

  // ---- gates ----
  gemm_head<64, 256, 1, 1><<<dim3(16, 16), 256, 0, stream>>>(
      feats, (size_t)0, gate_w1, gate_b1, gate_g1, gate_bb1, g1);
  gate23_k<<<2048, 256, 0, stream>>>(g1, gate_w2, gate_b2, gate_w3, gate_b3, sc);

  // ---- routing + outputs ----
  routing_k<<<1, 512, 0, stream>>>(sc, conf, lg, (float*)d_out);
}

// Round 18
// 725.684 us; speedup vs baseline: 1.2301x; 1.0044x over previous
//
#include <hip/hip_runtime.h>

// ============================================================================
// ImprovedMoE R18 = R17 + (a) B staging via __builtin_amdgcn_global_load_lds
// width=16 (removes per-ck ds_writes from the DS pipe + 20 VGPR bounce regs;
// DMA lands under the tap loop, barrier vmcnt-drains it), (b) cls_softmax +
// gate23 fused into one launch. Trunk math unchanged: D=(Ah+Al)*Bh.
// ============================================================================

typedef _Float16 h16;
typedef _Float16 half8 __attribute__((ext_vector_type(8)));
typedef float f32x16 __attribute__((ext_vector_type(16)));

__device__ __forceinline__ void split2f(float x, h16& hh, h16& ll) {
  h16 a = (h16)x;
  hh = a;
  ll = (h16)(x - (float)a);
}

__device__ __forceinline__ void dma_b16(const h16* g, h16* l) {
  __builtin_amdgcn_global_load_lds(
      (const __attribute__((address_space(1))) void*)g,
      (__attribute__((address_space(3))) void*)l, 16, 0, 0);
}

// ---- fused prep: zero pads + conv1 wt transpose + conv2..6 weight split ----
__global__ void prep_all_k(const float* __restrict__ cw1, const float* __restrict__ cw2,
                           const float* __restrict__ cw3, const float* __restrict__ cw4,
                           const float* __restrict__ cw5, const float* __restrict__ cw6,
                           float* __restrict__ wt1t, h16* __restrict__ wh,
                           h16* p0, h16* p1, h16* p2, h16* p3) {
  int idx = blockIdx.x * 256 + threadIdx.x;
  if (idx < 64) {
    h16* p = (idx < 16) ? p0 : (idx < 32) ? p1 : (idx < 48) ? p2 : p3;
    p[idx & 15] = (h16)0.f;
    return;
  }
  idx -= 64;
  if (idx < 1728) {
    int co = idx % 64, r = idx / 64;
    wt1t[idx] = cw1[(size_t)co * 27 + r];
    return;
  }
  idx -= 1728;
  const float* w; int CIN, COUT; size_t off;
  if (idx < 36864)        { w = cw2; CIN = 64;  COUT = 64;  off = 0; }
  else if (idx < 110592)  { w = cw3; CIN = 64;  COUT = 128; off = 36864;  idx -= 36864; }
  else if (idx < 258048)  { w = cw4; CIN = 128; COUT = 128; off = 110592; idx -= 110592; }
  else if (idx < 552960)  { w = cw5; CIN = 128; COUT = 256; off = 258048; idx -= 258048; }
  else if (idx < 1142784) { w = cw6; CIN = 256; COUT = 256; off = 552960; idx -= 552960; }
  else return;
  int KCOB = COUT >> 6;
  int lidx = idx;
  int c8   = idx & 7;
  int t    = idx >> 3;
  int co64 = t & 63;  t >>= 6;
  int half = t & 1;   t >>= 1;
  int cob  = t % KCOB; t /= KCOB;
  int tap  = t % 9;
  int ck   = t / 9;
  int ci = ck * 16 + half * 8 + c8;
  int co = cob * 64 + co64;
  float v = w[((size_t)co * CIN + ci) * 9 + tap];
  wh[off + lidx] = (h16)v;
}

// ---- conv1: 3->64, 32x32, fp32 vector; outputs blocked hi/lo planes (+16) ----
__global__ __launch_bounds__(256) void conv1_k(
    const float* __restrict__ x, const float* __restrict__ wt,
    const float* __restrict__ cb, const float* __restrict__ bns,
    const float* __restrict__ bnb, h16* __restrict__ oh, h16* __restrict__ ol)
{
  __shared__ float sx[3 * 34 * 34];
  const int tid = threadIdx.x;
  const int img = blockIdx.x;
  for (int idx = tid; idx < 3 * 34 * 34; idx += 256) {
    int xx = idx % 34;
    int t  = idx / 34;
    int rr = t % 34;
    int c  = t / 34;
    int gr = rr - 1, gx = xx - 1;
    float v = 0.f;
    if (gr >= 0 && gr < 32 && gx >= 0 && gx < 32)
      v = x[((size_t)(img * 3 + c) * 32 + gr) * 32 + gx];
    sx[(c * 34 + rr) * 34 + xx] = v;
  }
  __syncthreads();
#pragma unroll 1
  for (int k = 0; k < 4; ++k) {
    int px = k * 256 + tid;
    int yy = px >> 5, xx = px & 31;
    float in27[27];
#pragma unroll
    for (int c = 0; c < 3; ++c)
#pragma unroll
      for (int dy = 0; dy < 3; ++dy)
#pragma unroll
        for (int dx = 0; dx < 3; ++dx)
          in27[c * 9 + dy * 3 + dx] = sx[(c * 34 + yy + dy) * 34 + xx + dx];
#pragma unroll 1
    for (int cbk = 0; cbk < 4; ++cbk) {
      h16 hb[16], lb[16];
#pragma unroll
      for (int j = 0; j < 16; ++j) {
        int co = cbk * 16 + j;
        float acc = 0.f;
#pragma unroll
        for (int t = 0; t < 27; ++t) acc = fmaf(in27[t], wt[t * 64 + co], acc);
        float s = bns[co];
        float yv = fmaxf(fmaf(acc + cb[co], s, bnb[co]), 0.f);
        split2f(yv, hb[j], lb[j]);
      }
      size_t o = 16 + ((size_t)(img * 4 + cbk) * 1024 + px) * 16;
      *(half8*)&oh[o]     = *(half8*)&hb[0];
      *(half8*)&oh[o + 8] = *(half8*)&hb[8];
      *(half8*)&ol[o]     = *(half8*)&lb[0];
      *(half8*)&ol[o + 8] = *(half8*)&lb[8];
    }
  }
}

// ---------------------------------------------------------------------------
// MFMA conv: 3x3 SAME, tap-decomposed implicit GEMM. D = (Ah+Al)*Bh.
// Double-buffered B in LDS via global_load_lds DMA, ONE barrier/ck.
// A hi/lo direct-from-global with PF-deep prefetch; zero-pad sentinel halo.
// ---------------------------------------------------------------------------
template<int H, int W, int CIN, int COUT, int MT, int POOL, int OCC>
__global__ __launch_bounds__(256, OCC) void conv_mfma(
    const h16* __restrict__ Ah, const h16* __restrict__ Al,
    const h16* __restrict__ Wh,
    const float* __restrict__ cb, const float* __restrict__ bns,
    const float* __restrict__ bnb,
    h16* __restrict__ Oh, h16* __restrict__ Ol, float* __restrict__ feats)
{
  constexpr int TPI  = (H * W) / 32;
  constexpr int RPT  = 32 / W;
  constexpr int IPB  = (4 * MT * 32 >= H * W) ? (4 * MT * 32) / (H * W) : 1;
  constexpr int KC   = CIN / 16;
  constexpr int HW   = H * W;
  constexpr int KCO  = COUT / 16;
  constexpr int KCOB = COUT / 64;
  constexpr int LOGW = (W == 32) ? 5 : (W == 16) ? 4 : 3;
  constexpr int PF   = (MT == 1) ? 3 : 2;

  __shared__ h16 sBh[2][9 * 2 * 64 * 8];
  __shared__ float sRed[(POOL == 2 && MT == 1) ? 256 : 1];

  const int tid  = threadIdx.x;
  const int lane = tid & 63;
  const int wave = tid >> 6;
  const int half = lane >> 5;
  const int col  = lane & 31;
  const int cob  = blockIdx.z;
  const int co0  = cob * 64;

  int aoff[MT], ty[MT], tx[MT], img_t[MT], rw0[MT];
#pragma unroll
  for (int t = 0; t < MT; ++t) {
    int gt   = blockIdx.y * (4 * MT) + wave * MT + t;
    int img  = blockIdx.x * IPB + gt / TPI;
    int row0 = (gt % TPI) * RPT;
    int y = row0 + (col >> LOGW);
    int x = col & (W - 1);
    img_t[t] = img; rw0[t] = row0; ty[t] = y; tx[t] = x;
    aoff[t] = 16 + ((img * KC) * HW + y * W + x) * 16 + half * 8;
  }

  f32x16 acc[MT][2];
#pragma unroll
  for (int t = 0; t < MT; ++t)
#pragma unroll
    for (int n = 0; n < 2; ++n)
#pragma unroll
      for (int i = 0; i < 16; ++i) acc[t][n][i] = 0.f;

  // ---- DMA-stage B[0] into buffer 0 ----
#pragma unroll
  for (int i = 0; i < 5; ++i) {
    int id = tid + i * 256;
    if (id < 1152) {
      int src = ((id >> 7) * KCOB + cob) * 1024 + (id & 127) * 8;
      dma_b16(Wh + src, &sBh[0][id * 8]);
    }
  }
  __syncthreads();

  int buf = 0;
#pragma unroll 1
  for (int ck = 0; ck < KC; ++ck) {
    // ---- issue next ck's B DMA into the other buffer (lands under taps) ----
    const bool have_next = (ck + 1 < KC);
    if (have_next) {
#pragma unroll
      for (int i = 0; i < 5; ++i) {
        int id = tid + i * 256;
        if (id < 1152) {
          int src = (((ck + 1) * 9 + (id >> 7)) * KCOB + cob) * 1024 + (id & 127) * 8;
          dma_b16(Wh + src, &sBh[buf ^ 1][id * 8]);
        }
      }
    }

    const int ckoA = ck * (HW * 16);
    const h16* bB = sBh[buf];

    half8 pah[PF][MT], pal[PF][MT];
#pragma unroll
    for (int pt = 0; pt < PF; ++pt) {
      const int dy = pt / 3 - 1, dx = pt % 3 - 1;
      const int ashift = (dy * W + dx) * 16;
#pragma unroll
      for (int t = 0; t < MT; ++t) {
        bool v = ((unsigned)(ty[t] + dy) < (unsigned)H) &&
                 ((unsigned)(tx[t] + dx) < (unsigned)W);
        int ai = v ? (aoff[t] + ckoA + ashift) : (half * 8);
        pah[pt][t] = *(const half8*)(Ah + ai);
        pal[pt][t] = *(const half8*)(Al + ai);
      }
    }

#pragma unroll
    for (int tap = 0; tap < 9; ++tap) {
      const int bufr = tap % PF;
      half8 bh[2];
#pragma unroll
      for (int n = 0; n < 2; ++n) {
        int bi = ((tap * 2 + half) * 64 + n * 32 + col) * 8;
        bh[n] = *(const half8*)&bB[bi];
      }
      half8 cah[MT], cal[MT];
#pragma unroll
      for (int t = 0; t < MT; ++t) { cah[t] = pah[bufr][t]; cal[t] = pal[bufr][t]; }
      if (tap + PF < 9) {
        const int pt = tap + PF;
        const int dy = pt / 3 - 1, dx = pt % 3 - 1;
        const int ashift = (dy * W + dx) * 16;
#pragma unroll
        for (int t = 0; t < MT; ++t) {
          bool v = ((unsigned)(ty[t] + dy) < (unsigned)H) &&
                   ((unsigned)(tx[t] + dx) < (unsigned)W);
          int ai = v ? (aoff[t] + ckoA + ashift) : (half * 8);
          pah[bufr][t] = *(const half8*)(Ah + ai);
          pal[bufr][t] = *(const half8*)(Al + ai);
        }
      }
#pragma unroll
      for (int t = 0; t < MT; ++t)
#pragma unroll
        for (int n = 0; n < 2; ++n) {
          acc[t][n] = __builtin_amdgcn_mfma_f32_32x32x16_f16(cah[t], bh[n], acc[t][n], 0, 0, 0);
          acc[t][n] = __builtin_amdgcn_mfma_f32_32x32x16_f16(cal[t], bh[n], acc[t][n], 0, 0, 0);
        }
    }

    __syncthreads();   // drains the DMA (vmcnt) + orders buffer swap
    buf ^= 1;
  }

#pragma unroll
  for (int n = 0; n < 2; ++n) {
    const int co = co0 + n * 32 + col;
    const float es = bns[co];
    const float eb = fmaf(cb[co], es, bnb[co]);
    const int cko = co >> 4, c16 = co & 15;

    if constexpr (POOL == 0) {
#pragma unroll
      for (int t = 0; t < MT; ++t) {
#pragma unroll
        for (int r = 0; r < 16; ++r) {
          float v = fmaxf(fmaf(acc[t][n][r], es, eb), 0.f);
          int m = (r & 3) + 4 * half + 8 * (r >> 2);
          int y = rw0[t] + (m >> LOGW);
          int x = m & (W - 1);
          size_t oi = 16 + ((size_t)(img_t[t] * KCO + cko) * HW + y * W + x) * 16 + c16;
          h16 hh, ll; split2f(v, hh, ll);
          Oh[oi] = hh; Ol[oi] = ll;
        }
      }
    } else if constexpr (POOL == 1 && RPT == 1) {
      constexpr int HWq = (H / 2) * (W / 2);
#pragma unroll
      for (int tp = 0; tp < MT / 2; ++tp) {
        const int t0 = 2 * tp, t1 = 2 * tp + 1;
        const int yq = rw0[t0] >> 1;
#pragma unroll
        for (int r = 0; r < 16; r += 2) {
          float v00 = fmaxf(fmaf(acc[t0][n][r],     es, eb), 0.f);
          float v01 = fmaxf(fmaf(acc[t0][n][r + 1], es, eb), 0.f);
          float v10 = fmaxf(fmaf(acc[t1][n][r],     es, eb), 0.f);
          float v11 = fmaxf(fmaf(acc[t1][n][r + 1], es, eb), 0.f);
          float mv = fmaxf(fmaxf(v00, v01), fmaxf(v10, v11));
          int xq = ((r & 3) >> 1) + 2 * half + 4 * (r >> 2);
          size_t oi = 16 + ((size_t)(img_t[t0] * KCO + cko) * HWq + yq * (W / 2) + xq) * 16 + c16;
          h16 hh, ll; split2f(mv, hh, ll);
          Oh[oi] = hh; Ol[oi] = ll;
        }
      }
    } else if constexpr (POOL == 1) {
      constexpr int HWq = (H / 2) * (W / 2);
#pragma unroll
      for (int t = 0; t < MT; ++t) {
        const int yq = rw0[t] >> 1;
#pragma unroll
        for (int r = 0; r < 8; r += 2) {
          float v00 = fmaxf(fmaf(acc[t][n][r],     es, eb), 0.f);
          float v01 = fmaxf(fmaf(acc[t][n][r + 1], es, eb), 0.f);
          float v10 = fmaxf(fmaf(acc[t][n][r + 8], es, eb), 0.f);
          float v11 = fmaxf(fmaf(acc[t][n][r + 9], es, eb), 0.f);
          float mv = fmaxf(fmaxf(v00, v01), fmaxf(v10, v11));
          int xq = ((r & 3) >> 1) + 2 * half + 4 * (r >> 2);
          size_t oi = 16 + ((size_t)(img_t[t] * KCO + cko) * HWq + yq * (W / 2) + xq) * 16 + c16;
          h16 hh, ll; split2f(mv, hh, ll);
          Oh[oi] = hh; Ol[oi] = ll;
        }
      }
    } else if constexpr (POOL == 2 && MT == 1) {
      float s = 0.f;
#pragma unroll
      for (int r = 0; r < 16; ++r)
        s += fmaxf(fmaf(acc[0][n][r], es, eb), 0.f);
      s += __shfl_xor(s, 32, 64);
      if (half == 0) sRed[wave * 64 + n * 32 + col] = s;
    } else if constexpr (POOL == 2) {
      float s = 0.f;
#pragma unroll
      for (int t = 0; t < MT; ++t)
#pragma unroll
        for (int r = 0; r < 16; ++r)
          s += fmaxf(fmaf(acc[t][n][r], es, eb), 0.f);
      s += __shfl_xor(s, 32, 64);
      if (half == 0) feats[(size_t)img_t[0] * 256 + co] = s * (1.f / 64.f);
    }
  }

  if constexpr (POOL == 2 && MT == 1) {
    __syncthreads();
    if (tid < 128) {
      int li = tid >> 6, co_l = tid & 63;
      float s = sRed[(li * 2) * 64 + co_l] + sRed[(li * 2 + 1) * 64 + co_l];
      feats[(size_t)(blockIdx.x * 2 + li) * 256 + co0 + co_l] = s * (1.f / 64.f);
    }
  }
}

// ---------------------------------------------------------------------------
// Batched head GEMM: 32 batch rows/block (grid 256 blocks; R17-verified).
// ---------------------------------------------------------------------------
template<int O, int K, int LN, int RELU>
__global__ __launch_bounds__(256, 4) void gemm_head(
    const float* __restrict__ A, size_t aStrideE,
    const float* __restrict__ Wm, const float* __restrict__ bias,
    const float* __restrict__ g, const float* __restrict__ bb,
    float* __restrict__ out)
{
  constexpr int KC  = (O >= 256) ? 32 : 64;
  constexpr int WST = O + 4;
  constexpr int TO  = O / 16;
  __shared__ float sA[KC * 36];
  __shared__ float sW[KC * WST];
  __shared__ float mArr[32], rArr[32];

  const int tid  = threadIdx.x;
  const int lane = tid & 63;
  const int wave = tid >> 6;
  const int e    = blockIdx.y;
  const int b0g  = blockIdx.x * 32;
  const int bl   = (lane & 15) * 2;
  const int ol   = wave * (O / 4) + (lane >> 4) * TO;

  const float* Ae = A + (size_t)e * aStrideE;
  const float* We = Wm + (size_t)e * O * K;

  float acc[2][TO];
#pragma unroll
  for (int i = 0; i < 2; ++i)
#pragma unroll
    for (int j = 0; j < TO; ++j) acc[i][j] = 0.f;

  for (int k0 = 0; k0 < K; k0 += KC) {
    for (int idx = tid; idx < 32 * KC; idx += 256) {
      int kk = idx % KC, bb_ = idx / KC;
      sA[kk * 36 + bb_] = Ae[(size_t)(b0g + bb_) * K + k0 + kk];
    }
    for (int idx = tid; idx < O * KC; idx += 256) {
      int kk = idx % KC, oo = idx / KC;
      sW[kk * WST + oo] = We[(size_t)oo * K + k0 + kk];
    }
    __syncthreads();
#pragma unroll 4
    for (int kk = 0; kk < KC; ++kk) {
      float2 av = *(const float2*)&sA[kk * 36 + bl];
      float a2[2] = {av.x, av.y};
#pragma unroll
      for (int j4 = 0; j4 < TO; j4 += 4) {
        float4 wv = *(const float4*)&sW[kk * WST + ol + j4];
        float w4[4] = {wv.x, wv.y, wv.z, wv.w};
#pragma unroll
        for (int i = 0; i < 2; ++i)
#pragma unroll
          for (int jj = 0; jj < 4; ++jj)
            acc[i][j4 + jj] = fmaf(a2[i], w4[jj], acc[i][j4 + jj]);
      }
    }
    __syncthreads();
  }

  const float* bi = bias + (size_t)e * O;
#pragma unroll
  for (int i = 0; i < 2; ++i)
#pragma unroll
    for (int j = 0; j < TO; ++j) acc[i][j] += bi[ol + j];

  if constexpr (LN) {
    float* redS = sA;
    float* redQ = sA + 512;
    const int grp = wave * 4 + (lane >> 4);
#pragma unroll
    for (int i = 0; i < 2; ++i) {
      float s = 0.f, q = 0.f;
#pragma unroll
      for (int j = 0; j < TO; ++j) { s += acc[i][j]; q += acc[i][j] * acc[i][j]; }
      redS[(bl + i) * 16 + grp] = s;
      redQ[(bl + i) * 16 + grp] = q;
    }
    __syncthreads();
    if (tid < 32) {
      float s = 0.f, q = 0.f;
#pragma unroll
      for (int gi = 0; gi < 16; ++gi) { s += redS[tid * 16 + gi]; q += redQ[tid * 16 + gi]; }
      float mean = s * (1.f / O);
      float var  = q * (1.f / O) - mean * mean;
      mArr[tid] = mean;
      rArr[tid] = rsqrtf(var + 1e-5f);
    }
    __syncthreads();
    const float* gp  = g + (size_t)e * O;
    const float* bbp = bb + (size_t)e * O;
#pragma unroll
    for (int i = 0; i < 2; ++i) {
      float mean = mArr[bl + i], rstd = rArr[bl + i];
#pragma unroll
      for (int j = 0; j < TO; ++j)
        acc[i][j] = (acc[i][j] - mean) * rstd * gp[ol + j] + bbp[ol + j];
    }
  }
  if constexpr (RELU) {
#pragma unroll
    for (int i = 0; i < 2; ++i)
#pragma unroll
      for (int j = 0; j < TO; ++j) acc[i][j] = fmaxf(acc[i][j], 0.f);
  }
#pragma unroll
  for (int i = 0; i < 2; ++i) {
    float* op = out + ((size_t)e * 512 + b0g + bl + i) * O + ol;
#pragma unroll
    for (int j4 = 0; j4 < TO; j4 += 4)
      *(float4*)(op + j4) = make_float4(acc[i][j4], acc[i][j4 + 1], acc[i][j4 + 2], acc[i][j4 + 3]);
  }
}

// ---- fused cls_softmax + gate23: one wave per (b,e), both heads ----
__global__ void heads_small_k(const float* __restrict__ embeds,
                              const float* __restrict__ cw,
                              const float* __restrict__ cbias,
                              const float* __restrict__ g1, const float* __restrict__ w2,
                              const float* __restrict__ b2, const float* __restrict__ w3,
                              const float* __restrict__ b3,
                              float* __restrict__ logits_e, float* __restrict__ conf,
                              float* __restrict__ scores)
{
  int wv   = (blockIdx.x * 256 + threadIdx.x) >> 6;
  int lane = threadIdx.x & 63;
  int b = wv >> 4, e = wv & 15;

  // ---- cls + softmax + entropy ----
  const float* ep = embeds + ((size_t)e * 512 + b) * 128;
  float e0 = ep[lane], e1 = ep[lane + 64];
  float l[10];
#pragma unroll
  for (int o = 0; o < 10; ++o) {
    const float* wp = cw + ((size_t)e * 10 + o) * 128;
    l[o] = e0 * wp[lane] + e1 * wp[lane + 64];
  }
#pragma unroll
  for (int s = 32; s >= 1; s >>= 1)
#pragma unroll
    for (int o = 0; o < 10; ++o) l[o] += __shfl_xor(l[o], s, 64);
#pragma unroll
  for (int o = 0; o < 10; ++o) l[o] += cbias[e * 10 + o];
  float m = l[0];
#pragma unroll
  for (int o = 1; o < 10; ++o) m = fmaxf(m, l[o]);
  float p[10], sum = 0.f;
#pragma unroll
  for (int o = 0; o < 10; ++o) { p[o] = expf(l[o] - m); sum += p[o]; }
  float inv = 1.f / sum, ent = 0.f;
#pragma unroll
  for (int o = 0; o < 10; ++o) { float pp = p[o] * inv; ent -= pp * logf(pp + 1e-12f); }
  if (lane == 0) {
    conf[b * 16 + e] = -ent;
#pragma unroll
    for (int o = 0; o < 10; ++o) logits_e[((size_t)b * 16 + e) * 10 + o] = l[o];
  }

  // ---- gates 2+3 ----
  float gv = g1[((size_t)e * 512 + b) * 64 + lane];
  const float* w3p = w3 + e * 32;
  float sc = 0.f;
#pragma unroll
  for (int o = 0; o < 32; ++o) {
    float t = gv * w2[((size_t)e * 32 + o) * 64 + lane];
#pragma unroll
    for (int s = 32; s >= 1; s >>= 1) t += __shfl_xor(t, s, 64);
    float g2v = fmaxf(t + b2[e * 32 + o], 0.f);
    sc = fmaf(g2v, w3p[o], sc);
  }
  if (lane == 0) scores[b * 16 + e] = sc + b3[e];
}

__global__ void routing_k(const float* __restrict__ scores, const float* __restrict__ conf,
                          const float* __restrict__ logits_e, float* __restrict__ out)
{
  __shared__ int t2[512];
  __shared__ int chs[512];
  const int tid = threadIdx.x;

  if (tid < 512) {
    int b = tid;
    float v0 = -3.4e38f, v1 = -3.4e38f;
    int i0 = 0, i1 = 0;
#pragma unroll
    for (int e = 0; e < 16; ++e) {
      float s = scores[b * 16 + e];
      float c = conf[b * 16 + e];
      float v = 0.7f * s + 0.3f * c - 0.125f;
      out[5120 + b * 16 + e] = v;
      if (v > v0) { v1 = v0; i1 = i0; v0 = v; i0 = e; }
      else if (v > v1) { v1 = v; i1 = e; }
    }
    t2[b] = i0 | (i1 << 8);
  }
  __syncthreads();

  if (tid < 64) {
    int lane = tid;
    int cnt = 0;
    int pk[8];
#pragma unroll
    for (int k = 0; k < 8; ++k) pk[k] = t2[k * 64 + lane];
#pragma unroll 1
    for (int k = 0; k < 8; ++k) {
      for (int j = 0; j < 64; ++j) {
        int pair = __shfl(pk[k], j, 64);
        int i0 = pair & 0xff, i1 = (pair >> 8) & 0xff;
        int c0 = __shfl(cnt, i0, 64);
        int c1 = __shfl(cnt, i1, 64);
        int ch = (c0 < 64) ? i0 : ((c1 < 64) ? i1 : ((c0 <= c1) ? i0 : i1));
        cnt += (lane == ch) ? 1 : 0;
        if (lane == 0) chs[k * 64 + j] = ch;
      }
    }
  }
  __syncthreads();

  if (tid < 512) {
    int b = tid;
    int ch = chs[b];
#pragma unroll
    for (int e = 0; e < 16; ++e)
      out[13312 + b * 16 + e] = (e == ch) ? 1.0f : 0.0f;
#pragma unroll
    for (int o = 0; o < 10; ++o)
      out[b * 10 + o] = logits_e[((size_t)b * 16 + ch) * 10 + o];
  }
}

// ============================================================================
extern "C" void kernel_launch(void* const* d_in, const int* in_sizes, int n_in,
                              void* d_out, int out_size, void* d_ws, size_t ws_size,
                              hipStream_t stream) {
  (void)in_sizes; (void)n_in; (void)out_size; (void)ws_size;

  const float* x = (const float*)d_in[0];
  const float *cw[6], *cbv[6], *bsv[6], *bbv[6];
  for (int i = 0; i < 6; ++i) {
    cw[i]  = (const float*)d_in[1 + 4 * i];
    cbv[i] = (const float*)d_in[2 + 4 * i];
    bsv[i] = (const float*)d_in[3 + 4 * i];
    bbv[i] = (const float*)d_in[4 + 4 * i];
  }
  const float* gate_w1  = (const float*)d_in[25];
  const float* gate_b1  = (const float*)d_in[26];
  const float* gate_g1  = (const float*)d_in[27];
  const float* gate_bb1 = (const float*)d_in[28];
  const float* gate_w2  = (const float*)d_in[29];
  const float* gate_b2  = (const float*)d_in[30];
  const float* gate_w3  = (const float*)d_in[31];
  const float* gate_b3  = (const float*)d_in[32];
  const float* exp_w1   = (const float*)d_in[33];
  const float* exp_b1   = (const float*)d_in[34];
  const float* exp_g1   = (const float*)d_in[35];
  const float* exp_bb1  = (const float*)d_in[36];
  const float* exp_w2   = (const float*)d_in[37];
  const float* exp_b2   = (const float*)d_in[38];
  const float* exp_g2   = (const float*)d_in[39];
  const float* exp_bb2  = (const float*)d_in[40];
  const float* exp_w3   = (const float*)d_in[41];
  const float* exp_b3   = (const float*)d_in[42];
  const float* cls_w    = (const float*)d_in[43];
  const float* cls_b    = (const float*)d_in[44];

  char* wsb = (char*)d_ws;
  const size_t off_wt1t = 0;
  const size_t off_whi  = 6912;
  const size_t off_Phi  = 4578048;
  const size_t off_Plo  = 71687168;
  const size_t off_Qhi  = 138796288;
  const size_t off_Qlo  = 155573760;
  const size_t off_feats= 172351232;
  const size_t off_h1   = 138796288 + 512;
  const size_t off_h2   = off_h1 + 8388608;
  const size_t off_emb  = off_h2 + 4194304;
  const size_t off_g1   = off_emb + 4194304;
  const size_t off_lg   = off_g1 + 2097152;
  const size_t off_conf = off_lg + 327680;
  const size_t off_sc   = off_conf + 32768;

  float* wt1t = (float*)(wsb + off_wt1t);
  h16* whi = (h16*)(wsb + off_whi);
  h16* Phi = (h16*)(wsb + off_Phi);
  h16* Plo = (h16*)(wsb + off_Plo);
  h16* Qhi = (h16*)(wsb + off_Qhi);
  h16* Qlo = (h16*)(wsb + off_Qlo);
  float* feats = (float*)(wsb + off_feats);
  float* h1 = (float*)(wsb + off_h1);
  float* h2 = (float*)(wsb + off_h2);
  float* emb = (float*)(wsb + off_emb);
  float* g1 = (float*)(wsb + off_g1);
  float* lg = (float*)(wsb + off_lg);
  float* conf = (float*)(wsb + off_conf);
  float* sc = (float*)(wsb + off_sc);

  const size_t wo2 = 0;
  const size_t wo3 = 36864;
  const size_t wo4 = 110592;
  const size_t wo5 = 258048;
  const size_t wo6 = 552960;

  // ---- fused prep (pads + wt1 transpose + all weight splits) ----
  prep_all_k<<<4471, 256, 0, stream>>>(cw[0], cw[1], cw[2], cw[3], cw[4], cw[5],
                                       wt1t, whi, Phi, Plo, Qhi, Qlo);

  // ---- trunk ----
  conv1_k<<<512, 256, 0, stream>>>(x, wt1t, cbv[0], bsv[0], bbv[0], Phi, Plo);
  // <H, W, CIN, COUT, MT, POOL, OCC>
  conv_mfma<32, 32, 64, 64, 2, 1, 3><<<dim3(512, 4, 1), 256, 0, stream>>>(
      Phi, Plo, whi + wo2, cbv[1], bsv[1], bbv[1], Qhi, Qlo, nullptr);
  conv_mfma<16, 16, 64, 128, 2, 0, 3><<<dim3(512, 1, 2), 256, 0, stream>>>(
      Qhi, Qlo, whi + wo3, cbv[2], bsv[2], bbv[2], Phi, Plo, nullptr);
  conv_mfma<16, 16, 128, 128, 2, 1, 3><<<dim3(512, 1, 2), 256, 0, stream>>>(
      Phi, Plo, whi + wo4, cbv[3], bsv[3], bbv[3], Qhi, Qlo, nullptr);
  conv_mfma<8, 8, 128, 256, 1, 0, 4><<<dim3(256, 1, 4), 256, 0, stream>>>(
      Qhi, Qlo, whi + wo5, cbv[4], bsv[4], bbv[4], Phi, Plo, nullptr);
  conv_mfma<8, 8, 256, 256, 1, 2, 4><<<dim3(256, 1, 4), 256, 0, stream>>>(
      Phi, Plo, whi + wo6, cbv[5], bsv[5], bbv[5], nullptr, nullptr, feats);

  // ---- experts + gates (gate gemm hoisted before fused small heads) ----
  gemm_head<256, 256, 1, 1><<<dim3(16, 16), 256, 0, stream>>>(
      feats, (size_t)0, exp_w1, exp_b1, exp_g1, exp_bb1, h1);
  gemm_head<64, 256, 1, 1><<<dim3(16, 16), 256, 0, stream>>>(
      feats, (size_t)0, gate_w1, gate_b1, gate_g1, gate_bb1, g1);
  gemm_head<128, 256, 1, 1><<<dim3(16, 16), 256, 0, stream>>>(
      h1, (size_t)512 * 256, exp_w2, exp_b2, exp_g2, exp_bb2, h2);
  gemm_head<128, 128, 0, 0><<<dim3(16, 16), 256, 0, stream>>>(
      h2, (size_t)512 * 128, exp_w3, exp_b3, nullptr, nullptr, emb);
  heads_small_k<<<2048, 256, 0, stream>>>(emb, cls_w, cls_b,
                                          g1, gate_w2, gate_b2, gate_w3, gate_b3,
                                          lg, conf, sc);

  // ---- routing + outputs ----
  routing_k<<<1, 512, 0, stream>>>(sc, conf, lg, (float*)d_out);
}